// Round 5
// baseline (1158.113 us; speedup 1.0000x reference)
//
#include <hip/hip_runtime.h>
#include <math.h>

#define MDIM 1024
#define TSEQ 2048
#define NSOL 5
#define DED  64
#define NBLK 3
#define KITER 5
#define XLDB 1088   // bf16 X leading dim: 1024 sp cols + 64 demb cols
#define NRED 6144   // 5120 P cols + 1024 mp cols
#define NDB  64     // dirty-head grid size

typedef __bf16 bf16x8 __attribute__((ext_vector_type(8)));
typedef __bf16 bf16x4 __attribute__((ext_vector_type(4)));
typedef float  f32x4  __attribute__((ext_vector_type(4)));

#define GLDS16(gptr, lptr) __builtin_amdgcn_global_load_lds( \
    (const __attribute__((address_space(1))) unsigned int*)(const void*)(gptr), \
    (__attribute__((address_space(3))) unsigned int*)(void*)(lptr), 16, 0, 0)

__device__ __forceinline__ float gelu_f(float x){
  return 0.5f * x * (1.0f + erff(x * 0.70710678118654752440f));
}
__device__ __forceinline__ float sigmoid_f(float x){ return 1.0f/(1.0f+expf(-x)); }
__device__ __forceinline__ float softplus_f(float x){ return fmaxf(x,0.0f) + log1pf(expf(-fabsf(x))); }

// ---------------- init speculative state ----------------
__global__ void k_init(float* prevg, int* dlist, int* dcnt){
  int i = blockIdx.x*blockDim.x + threadIdx.x;
  if (i < TSEQ){ prevg[i] = (i==0)? -1.0f : 1.0f; dlist[i] = i; }
  if (i == 0) *dcnt = TSEQ;
}

// ---------------- fused convert fp32 [K][N] -> bf16 transposed [N][K], 12 blocks of 4 srcs ----------------
__global__ __launch_bounds__(256) void k_cvtT12(const float* __restrict__ s0,
    const float* __restrict__ s1, const float* __restrict__ s2, const float* __restrict__ s3,
    __bf16* __restrict__ dst){
  __shared__ float t[32][33];
  const size_t MM = (size_t)MDIM*MDIM;
  int z = blockIdx.z;
  const float* s = (z<3)? s0 + (size_t)z*MM : (z<6)? s1 + (size_t)(z-3)*MM :
                   (z<9)? s2 + (size_t)(z-6)*MM : s3 + (size_t)(z-9)*MM;
  __bf16* d = dst + (size_t)z*MM;
  int k0 = blockIdx.y*32, n0 = blockIdx.x*32;
  int tx = threadIdx.x & 31, ty = threadIdx.x >> 5;
  #pragma unroll
  for (int r=0;r<32;r+=8) t[ty+r][tx] = s[(size_t)(k0+ty+r)*MDIM + n0+tx];
  __syncthreads();
  #pragma unroll
  for (int r=0;r<32;r+=8) d[(size_t)(n0+ty+r)*MDIM + k0+tx] = (__bf16)t[tx][ty+r];
}

// single-matrix version (for WpT, K=1088)
__global__ __launch_bounds__(256) void k_cvtT(const float* __restrict__ src,
                                              __bf16* __restrict__ dst, int K, int N){
  __shared__ float t[32][33];
  int k0 = blockIdx.y*32, n0 = blockIdx.x*32;
  int tx = threadIdx.x & 31, ty = threadIdx.x >> 5;
  #pragma unroll
  for (int r=0;r<32;r+=8) t[ty+r][tx] = src[(size_t)(k0+ty+r)*N + n0+tx];
  __syncthreads();
  #pragma unroll
  for (int r=0;r<32;r+=8) dst[(size_t)(n0+ty+r)*K + k0+tx] = (__bf16)t[tx][ty+r];
}

// ---------------- partial matvecs: P parts (solvent, y=0..4) + mol part (y=5) ----------------
__global__ __launch_bounds__(256) void k_pm(const float* __restrict__ sv,
    const float* __restrict__ spW, const float* __restrict__ mol,
    const float* __restrict__ bhw, float* __restrict__ PART){
  int s = blockIdx.y;
  int j = blockIdx.x*256 + threadIdx.x;
  int z = blockIdx.z, k0 = z*64;
  if (s < NSOL){
    const float* w = spW + (size_t)s*MDIM*MDIM + (size_t)k0*MDIM + j;
    const float* v = sv + s*MDIM + k0;
    float acc = 0.f;
    for (int k=0;k<64;k++) acc = fmaf(v[k], w[(size_t)k*MDIM], acc);
    PART[(size_t)z*NRED + s*MDIM + j] = acc;
  } else {
    const float* w = bhw + (size_t)k0*MDIM + j;
    float acc = 0.f;
    for (int k=0;k<64;k++) acc = fmaf(mol[k0+k], w[(size_t)k*MDIM], acc);
    PART[(size_t)z*NRED + 5120 + j] = acc;
  }
}

// ---------------- reduce partials -> P, mp(+bias) ----------------
__global__ __launch_bounds__(256) void k_red(const float* __restrict__ PART,
    const float* __restrict__ bhb, float* __restrict__ P, float* __restrict__ mp){
  int i = blockIdx.x*256 + threadIdx.x;
  float a = 0.f;
  #pragma unroll
  for (int z=0;z<16;z++) a += PART[(size_t)z*NRED + i];
  if (i < 5120) P[i] = a;
  else mp[i-5120] = a + bhb[i-5120];
}

// ---------------- fused sp0 + demb ----------------
__global__ __launch_bounds__(256) void k_sp0d(const float* __restrict__ ratios,
    const float* __restrict__ P, const float* __restrict__ bias,
    const float* __restrict__ desc, const float* __restrict__ dw,
    const float* __restrict__ db,
    float* __restrict__ X, __bf16* __restrict__ Xb){
  int t = blockIdx.y;
  if (blockIdx.x < 4){
    int j = blockIdx.x*256 + threadIdx.x;
    const float* r = ratios + t*NSOL;
    float acc = bias[j];
    #pragma unroll
    for (int s=0;s<NSOL;s++) acc = fmaf(r[s], P[s*MDIM+j], acc);
    float v = gelu_f(acc);
    X[(size_t)t*MDIM + j] = v;
    Xb[(size_t)t*XLDB + j] = (__bf16)v;
  } else if (threadIdx.x < DED){
    int e = threadIdx.x;
    const float* d = desc + t*6;
    float acc = db[e];
    #pragma unroll
    for (int c=0;c<6;c++) acc = fmaf(d[c], dw[c*DED+e], acc);
    Xb[(size_t)t*XLDB + MDIM + e] = (__bf16)gelu_f(acc);
  }
}

// ---------------- bf16 MFMA GEMM, glds + chunk-swizzle + 2-phase dbuf, 512 thr ----------------
// BM=128, BN=64, template BK. 8 waves (4r x 2c), each 32x32 = 2x2 16x16 frags.
template<int BK, bool GELU, bool RES, bool OUTF, bool OUTB, bool Z0>
__global__ __launch_bounds__(512) void k_mfma_gemm(
    const __bf16* __restrict__ A, int lda, int K,
    const __bf16* __restrict__ Bt,           // [N][K] bf16
    const float* __restrict__ bias,          // [N] fp32
    const float* __restrict__ R, int ldr,    // fp32 residual
    float* __restrict__ Cf, int ldcf,
    __bf16* __restrict__ Cb, int ldcb,
    const float* __restrict__ wlast, const float* __restrict__ prevg,
    float* __restrict__ Z0f, __bf16* __restrict__ Z0b)
{
  constexpr int CPR = BK/8;        // 16B chunks per row
  constexpr int AG  = BK/32;       // A stage groups per thread
  constexpr int BG  = (BK>=64)? BK/64 : 1;
  constexpr int KS  = BK/32;       // k-subtiles per tile
  __shared__ __attribute__((aligned(16))) __bf16 As[2][128*BK];
  __shared__ __attribute__((aligned(16))) __bf16 Bs[2][64*BK];
  int tid = threadIdx.x;
  int wave = tid>>6, lane = tid&63;
  int row0 = blockIdx.y*128, col0 = blockIdx.x*64;
  int wr = (wave>>1)*32, wc = (wave&1)*32;
  int lr = lane&15;
  f32x4 acc[2][2] = {};
  int NT = K / BK;

  auto stage = [&](int b, int k0){
    #pragma unroll
    for (int p=0;p<AG;p++){
      int q = wave*(AG*64) + p*64 + lane;      // A chunk id
      int r = q/CPR, c = q%CPR, cl = c^(r&7);
      GLDS16(A + (size_t)(row0+r)*lda + k0 + cl*8, &As[b][(wave*(AG*64)+p*64)*8]);
    }
    #pragma unroll
    for (int p=0;p<BG;p++){
      int q = wave*(BG*64) + p*64 + lane;      // B chunk id
      int r = q/CPR, c = q%CPR, cl = c^(r&7);
      GLDS16(Bt + (size_t)(col0+r)*K + k0 + cl*8, &Bs[b][(wave*(BG*64)+p*64)*8]);
    }
  };

  stage(0, 0);
  for (int t=0; t<NT; t++){
    __syncthreads();                           // drains stage(t) + protects buffer reuse
    if (t+1 < NT) stage((t+1)&1, (t+1)*BK);    // issue next tile's loads
    int b = t&1;
    #pragma unroll
    for (int ks=0;ks<KS;ks++){
      int c = ks*4 + (lane>>4);                // logical chunk = kk>>3
      bf16x8 af[2], bg[2];
      #pragma unroll
      for (int m=0;m<2;m++){
        int rowA = wr + m*16 + lr;
        af[m] = *(const bf16x8*)&As[b][rowA*BK + ((c ^ (rowA&7))<<3)];
      }
      #pragma unroll
      for (int n=0;n<2;n++){
        int rowB = wc + n*16 + lr;
        bg[n] = *(const bf16x8*)&Bs[b][rowB*BK + ((c ^ (rowB&7))<<3)];
      }
      #pragma unroll
      for (int m=0;m<2;m++)
        #pragma unroll
        for (int n=0;n<2;n++)
          acc[m][n] = __builtin_amdgcn_mfma_f32_16x16x32_bf16(af[m], bg[n], acc[m][n], 0,0,0);
    }
  }
  int rq = (lane>>4)*4;  // verified C/D layout: col = lane&15, row = (lane>>4)*4 + q
  #pragma unroll
  for (int m=0;m<2;m++){
    #pragma unroll
    for (int n=0;n<2;n++){
      int cc = col0 + wc + n*16 + lr;
      float bv = bias[cc];
      #pragma unroll
      for (int q=0;q<4;q++){
        int r = row0 + wr + m*16 + rq + q;
        float v = acc[m][n][q] + bv;
        if (RES)  v += R[(size_t)r*ldr + cc];
        if (GELU) v = gelu_f(v);
        if (OUTF) Cf[(size_t)r*ldcf + cc] = v;
        if (OUTB) Cb[(size_t)r*ldcb + cc] = (__bf16)v;
        if (Z0){
          float z = gelu_f(v + prevg[r]*wlast[cc]);
          Z0f[(size_t)r*MDIM + cc] = z;
          Z0b[(size_t)r*MDIM + cc] = (__bf16)z;
        }
      }
    }
  }
}

// ---------------- batched LayerNorm (float4) -> fp32 + bf16, optional fused mu/phi ----------------
template<bool MUPHI>
__global__ __launch_bounds__(256) void k_ln(const float* __restrict__ Y, int ldy,
    float* __restrict__ Xo, int ldx, __bf16* __restrict__ Xb, int ldxb,
    const float* __restrict__ g, const float* __restrict__ b,
    const float* __restrict__ muw, const float* __restrict__ mub,
    const float* __restrict__ phiw, const float* __restrict__ phib,
    float* __restrict__ muA, float* __restrict__ phiA)
{
  int t = blockIdx.x;
  __shared__ float red[16];
  int tid = threadIdx.x;
  f32x4 y = *(const f32x4*)&Y[(size_t)t*ldy + tid*4];
  float s  = y[0]+y[1]+y[2]+y[3];
  float s2 = y[0]*y[0]+y[1]*y[1]+y[2]*y[2]+y[3]*y[3];
  for (int o=32;o>0;o>>=1){ s += __shfl_down(s,o); s2 += __shfl_down(s2,o); }
  int wid = tid>>6, lane = tid&63;
  if (lane==0){ red[wid]=s; red[wid+8]=s2; }
  __syncthreads();
  if (tid==0){
    float a=0.f,c=0.f;
    for (int w=0;w<4;w++){ a+=red[w]; c+=red[w+8]; }
    red[0]=a; red[8]=c;
  }
  __syncthreads();
  float mean = red[0]*(1.0f/MDIM);
  float var  = red[8]*(1.0f/MDIM) - mean*mean;
  float rs = rsqrtf(var + 1e-5f);
  f32x4 gv = *(const f32x4*)&g[tid*4];
  f32x4 bb = *(const f32x4*)&b[tid*4];
  f32x4 v; bf16x4 vb;
  #pragma unroll
  for (int i=0;i<4;i++){ v[i] = gv[i]*(y[i]-mean)*rs + bb[i]; vb[i] = (__bf16)v[i]; }
  *(f32x4*)&Xo[(size_t)t*ldx + tid*4] = v;
  *(bf16x4*)&Xb[(size_t)t*ldxb + tid*4] = vb;
  if (MUPHI){
    f32x4 mw = *(const f32x4*)&muw[tid*4];
    f32x4 pw = *(const f32x4*)&phiw[tid*4];
    float sm=0.f, sp=0.f;
    #pragma unroll
    for (int i=0;i<4;i++){ sm = fmaf(v[i], mw[i], sm); sp = fmaf(v[i], pw[i], sp); }
    for (int o=32;o>0;o>>=1){ sm+=__shfl_down(sm,o); sp+=__shfl_down(sp,o); }
    __syncthreads();
    if (lane==0){ red[wid]=sm; red[wid+8]=sp; }
    __syncthreads();
    if (tid==0){
      float a=0.f,c=0.f;
      for (int w=0;w<4;w++){ a+=red[w]; c+=red[w+8]; }
      muA[t]  = sigmoid_f(a + mub[0]);
      phiA[t] = softplus_f(c + phib[0]) + 2.0f;
    }
  }
}

// ---------------- fused full-head refinement for dirty rows (one block per row) ----------------
__global__ __launch_bounds__(1024) void k_head_dirty(
    const float* __restrict__ ZP, const float* __restrict__ wlast,
    const float* __restrict__ prevg,
    const __bf16* __restrict__ U1T, const __bf16* __restrict__ U2T,
    const float* __restrict__ fc1b, const float* __restrict__ fc2b,
    const float* __restrict__ lng,  const float* __restrict__ lnb,
    const float* __restrict__ muw,  const float* __restrict__ mub,
    const float* __restrict__ phiw, const float* __restrict__ phib,
    const int* __restrict__ dlist, const int* __restrict__ dcnt,
    float* __restrict__ muA, float* __restrict__ phiA)
{
  int nd = *dcnt;
  if (nd == 0) return;
  __shared__ __bf16 zb[MDIM];
  __shared__ float  zf[MDIM];
  __shared__ __bf16 hb[MDIM];
  __shared__ float  red[32];
  const size_t MM = (size_t)MDIM*MDIM;
  int j = threadIdx.x;
  int wid = j>>6, lane = j&63;
  for (int rs = blockIdx.x; rs < nd; rs += NDB){
    int t = dlist[rs];
    float prev = prevg[t];
    float v0 = gelu_f(ZP[(size_t)t*MDIM + j] + prev*wlast[j]);
    zf[j] = v0; zb[j] = (__bf16)v0;
    __syncthreads();
    for (int blk=0; blk<NBLK; blk++){
      // fc1
      {
        const __bf16* w = U1T + blk*MM + (size_t)j*MDIM;
        float acc = 0.f;
        for (int k=0;k<MDIM;k+=16){
          bf16x8 w0 = *(const bf16x8*)&w[k];
          bf16x8 w1 = *(const bf16x8*)&w[k+8];
          bf16x8 i0 = *(const bf16x8*)&zb[k];
          bf16x8 i1 = *(const bf16x8*)&zb[k+8];
          #pragma unroll
          for (int u=0;u<8;u++){
            acc = fmaf((float)w0[u], (float)i0[u], acc);
            acc = fmaf((float)w1[u], (float)i1[u], acc);
          }
        }
        hb[j] = (__bf16)gelu_f(acc + fc1b[blk*MDIM + j]);
      }
      __syncthreads();
      // fc2 + residual
      float y;
      {
        const __bf16* w = U2T + blk*MM + (size_t)j*MDIM;
        float acc = 0.f;
        for (int k=0;k<MDIM;k+=16){
          bf16x8 w0 = *(const bf16x8*)&w[k];
          bf16x8 w1 = *(const bf16x8*)&w[k+8];
          bf16x8 i0 = *(const bf16x8*)&hb[k];
          bf16x8 i1 = *(const bf16x8*)&hb[k+8];
          #pragma unroll
          for (int u=0;u<8;u++){
            acc = fmaf((float)w0[u], (float)i0[u], acc);
            acc = fmaf((float)w1[u], (float)i1[u], acc);
          }
        }
        y = acc + fc2b[blk*MDIM + j] + zf[j];
      }
      // LN
      float s = y, s2 = y*y;
      for (int o=32;o>0;o>>=1){ s+=__shfl_down(s,o); s2+=__shfl_down(s2,o); }
      if (lane==0){ red[wid]=s; red[wid+16]=s2; }
      __syncthreads();
      if (wid==0){
        float a = (lane<16)? red[lane] : 0.f;
        float c = (lane<16)? red[lane+16] : 0.f;
        for (int o=8;o>0;o>>=1){ a+=__shfl_down(a,o); c+=__shfl_down(c,o); }
        if (lane==0){ red[0]=a; red[16]=c; }
      }
      __syncthreads();
      float mean = red[0]*(1.0f/MDIM);
      float var  = red[16]*(1.0f/MDIM) - mean*mean;
      float rs2 = rsqrtf(var + 1e-5f);
      float zn = lng[blk*MDIM+j]*(y-mean)*rs2 + lnb[blk*MDIM+j];
      __syncthreads();
      zf[j] = zn; zb[j] = (__bf16)zn;
      __syncthreads();
    }
    // mu/phi
    float sm = zf[j]*muw[j];
    float sp = zf[j]*phiw[j];
    for (int o=32;o>0;o>>=1){ sm+=__shfl_down(sm,o); sp+=__shfl_down(sp,o); }
    if (lane==0){ red[wid]=sm; red[wid+16]=sp; }
    __syncthreads();
    if (wid==0){
      float a = (lane<16)? red[lane] : 0.f;
      float c = (lane<16)? red[lane+16] : 0.f;
      for (int o=8;o>0;o>>=1){ a+=__shfl_down(a,o); c+=__shfl_down(c,o); }
      if (lane==0){
        muA[t]  = sigmoid_f(a + mub[0]);
        phiA[t] = softplus_f(c + phib[0]) + 2.0f;
      }
    }
    __syncthreads();
  }
}

// ---------------- segmented prefix-product scan + dirty detection + output ----------------
__global__ __launch_bounds__(1024) void k_scan(
    const float* __restrict__ muA, const float* __restrict__ phiA,
    const unsigned char* __restrict__ bmask,
    float* __restrict__ prevg, int* __restrict__ dlist, int* __restrict__ dcnt,
    float* __restrict__ out)
{
  if (*dcnt == 0) return;   // converged: nothing changed since last scan
  __shared__ float v[2][TSEQ];
  __shared__ unsigned char f[2][TSEQ];
  __shared__ int cnt;
  int tid = threadIdx.x;
  if (tid==0) cnt = 0;
  for (int i=tid;i<TSEQ;i+=1024){
    v[0][i] = 1.0f - muA[i];
    f[0][i] = (i==0) || (bmask[i] != 0);
  }
  __syncthreads();
  int src=0;
  for (int off=1; off<TSEQ; off<<=1){
    int dst = src^1;
    for (int i=tid;i<TSEQ;i+=1024){
      float vv = v[src][i]; unsigned char ff = f[src][i];
      if (i>=off && !ff){ vv *= v[src][i-off]; ff = f[src][i-off]; }
      v[dst][i]=vv; f[dst][i]=ff;
    }
    __syncthreads();
    src = dst;
  }
  for (int i=tid;i<TSEQ;i+=1024){
    float rf = 1.0f - v[src][i];
    float prev = (i==0) ? -1.0f : (1.0f - v[src][i-1]);
    out[i]        = rf;
    out[TSEQ+i]   = muA[i];
    out[2*TSEQ+i] = phiA[i];
    float old = prevg[i];
    prevg[i] = prev;
    if (fabsf(prev - old) > 1e-4f){
      int pos = atomicAdd(&cnt, 1);
      dlist[pos] = i;
    }
  }
  __syncthreads();
  if (tid==0) *dcnt = cnt;
}

extern "C" void kernel_launch(void* const* d_in, const int* in_sizes, int n_in,
                              void* d_out, int out_size, void* d_ws, size_t ws_size,
                              hipStream_t stream) {
  const float* mol       = (const float*)d_in[0];
  const float* ratios    = (const float*)d_in[1];
  const float* desc      = (const float*)d_in[2];
  const float* svvec     = (const float*)d_in[3];
  const unsigned char* bmask = (const unsigned char*)d_in[4];
  const float* sp_proj_w = (const float*)d_in[5];
  const float* sp_proj_b = (const float*)d_in[6];
  const float* sp_fc1_w  = (const float*)d_in[7];
  const float* sp_fc1_b  = (const float*)d_in[8];
  const float* sp_fc2_w  = (const float*)d_in[9];
  const float* sp_fc2_b  = (const float*)d_in[10];
  const float* sp_ln_g   = (const float*)d_in[11];
  const float* sp_ln_b   = (const float*)d_in[12];
  const float* desc_w    = (const float*)d_in[13];
  const float* desc_b    = (const float*)d_in[14];
  const float* bh_proj_w = (const float*)d_in[15];
  const float* bh_proj_b = (const float*)d_in[16];
  const float* bh_fc1_w  = (const float*)d_in[17];
  const float* bh_fc1_b  = (const float*)d_in[18];
  const float* bh_fc2_w  = (const float*)d_in[19];
  const float* bh_fc2_b  = (const float*)d_in[20];
  const float* bh_ln_g   = (const float*)d_in[21];
  const float* bh_ln_b   = (const float*)d_in[22];
  const float* mu_w      = (const float*)d_in[23];
  const float* mu_b      = (const float*)d_in[24];
  const float* phi_w     = (const float*)d_in[25];
  const float* phi_b     = (const float*)d_in[26];
  float* out = (float*)d_out;

  char* p = (char*)d_ws;
  auto alloc = [&](size_t bytes)->char*{ char* r = p; p += (bytes + 255) & ~(size_t)255; return r; };
  const size_t MM = (size_t)MDIM*MDIM;
  float*  X    = (float*)alloc((size_t)TSEQ*MDIM*4);     // fp32 activations (sp x, later head z)
  __bf16* Xb   = (__bf16*)alloc((size_t)TSEQ*XLDB*2);    // bf16 [sp|demb]
  __bf16* Zb   = (__bf16*)alloc((size_t)TSEQ*MDIM*2);    // head bf16 z (separate: no alias w/ Xb)
  float*  Y    = (float*)alloc((size_t)TSEQ*MDIM*4);     // fp32 pre-LN
  float*  ZP   = (float*)alloc((size_t)TSEQ*MDIM*4);     // persistent head pre-activation
  __bf16* Hb16 = (__bf16*)alloc((size_t)TSEQ*MDIM*2);
  __bf16* WALL = (__bf16*)alloc(12*MM*2);                // W1T|W2T|U1T|U2T (3 blocks each)
  __bf16* WpT  = (__bf16*)alloc((size_t)MDIM*XLDB*2);    // [1024][1088]
  float*  PART = (float*)alloc((size_t)16*NRED*4);
  float*  P    = (float*)alloc((size_t)NSOL*MDIM*4);
  float*  mp   = (float*)alloc(MDIM*4);
  float*  prevg= (float*)alloc(TSEQ*4);
  float*  muA  = (float*)alloc(TSEQ*4);
  float*  phiA = (float*)alloc(TSEQ*4);
  int*    dlist= (int*)alloc(TSEQ*4);
  int*    dcnt = (int*)alloc(256);
  __bf16* W1T = WALL, *W2T = WALL + 3*MM, *U1T = WALL + 6*MM, *U2T = WALL + 9*MM;
  float*  Z    = X;      // alias: X fp32 dead after sp chain (zpre GEMM reads only Xb)

  k_init<<<dim3((TSEQ+255)/256),256,0,stream>>>(prevg, dlist, dcnt);
  k_cvtT12<<<dim3(32,32,12),256,0,stream>>>(sp_fc1_w, sp_fc2_w, bh_fc1_w, bh_fc2_w, WALL);
  k_cvtT<<<dim3(32,34,1),256,0,stream>>>(bh_proj_w + MM, WpT, XLDB, MDIM);

  k_pm<<<dim3(4,6,16),256,0,stream>>>(svvec, sp_proj_w, mol, bh_proj_w, PART);
  k_red<<<dim3(NRED/256),256,0,stream>>>(PART, bh_proj_b, P, mp);
  k_sp0d<<<dim3(5,TSEQ),256,0,stream>>>(ratios, P, sp_proj_b, desc, desc_w, desc_b, X, Xb);

  const float* wlast = bh_proj_w + (size_t)2112*MDIM;
  // sp residual chain (bf16 MFMA GEMMs, BK=128)
  for (int i=0;i<NBLK;i++){
    k_mfma_gemm<128,true,false,false,true,false><<<dim3(16,16),512,0,stream>>>(
        Xb, XLDB, MDIM, W1T + i*MM, sp_fc1_b + i*MDIM, nullptr, 0,
        nullptr, 0, Hb16, MDIM, nullptr, nullptr, nullptr, nullptr);
    k_mfma_gemm<128,false,true,true,false,false><<<dim3(16,16),512,0,stream>>>(
        Hb16, MDIM, MDIM, W2T + i*MM, sp_fc2_b + i*MDIM, X, MDIM,
        Y, MDIM, nullptr, 0, nullptr, nullptr, nullptr, nullptr);
    k_ln<false><<<dim3(TSEQ),256,0,stream>>>(Y, MDIM, X, MDIM, Xb, XLDB,
        sp_ln_g + i*MDIM, sp_ln_b + i*MDIM,
        nullptr, nullptr, nullptr, nullptr, nullptr, nullptr);
  }
  // z_pre GEMM (K=1088, BK=64) with fused z0 epilogue: ZP + speculative gelu -> Z/Zb
  k_mfma_gemm<64,false,false,true,false,true><<<dim3(16,16),512,0,stream>>>(
      Xb, XLDB, XLDB, WpT, mp, nullptr, 0, ZP, MDIM, nullptr, 0,
      wlast, prevg, Z, Zb);

  // ---- iteration 1: batched head with speculative prev ----
  for (int i=0;i<NBLK;i++){
    k_mfma_gemm<128,true,false,false,true,false><<<dim3(16,16),512,0,stream>>>(
        Zb, MDIM, MDIM, U1T + i*MM, bh_fc1_b + i*MDIM, nullptr, 0,
        nullptr, 0, Hb16, MDIM, nullptr, nullptr, nullptr, nullptr);
    k_mfma_gemm<128,false,true,true,false,false><<<dim3(16,16),512,0,stream>>>(
        Hb16, MDIM, MDIM, U2T + i*MM, bh_fc2_b + i*MDIM, Z, MDIM,
        Y, MDIM, nullptr, 0, nullptr, nullptr, nullptr, nullptr);
    if (i < NBLK-1)
      k_ln<false><<<dim3(TSEQ),256,0,stream>>>(Y, MDIM, Z, MDIM, Zb, MDIM,
          bh_ln_g + i*MDIM, bh_ln_b + i*MDIM,
          nullptr, nullptr, nullptr, nullptr, nullptr, nullptr);
    else
      k_ln<true><<<dim3(TSEQ),256,0,stream>>>(Y, MDIM, Z, MDIM, Zb, MDIM,
          bh_ln_g + i*MDIM, bh_ln_b + i*MDIM,
          mu_w, mu_b, phi_w, phi_b, muA, phiA);
  }
  k_scan<<<dim3(1),1024,0,stream>>>(muA, phiA, bmask, prevg, dlist, dcnt, out);

  // ---- refinement: fused full-head on dirty rows, then rescan ----
  for (int it=1; it<KITER; it++){
    k_head_dirty<<<dim3(NDB),1024,0,stream>>>(ZP, wlast, prevg, U1T, U2T,
        bh_fc1_b, bh_fc2_b, bh_ln_g, bh_ln_b,
        mu_w, mu_b, phi_w, phi_b, dlist, dcnt, muA, phiA);
    k_scan<<<dim3(1),1024,0,stream>>>(muA, phiA, bmask, prevg, dlist, dcnt, out);
  }
  (void)in_sizes; (void)n_in; (void)out_size; (void)ws_size;
}

// Round 6
// 446.263 us; speedup vs baseline: 2.5951x; 2.5951x over previous
//
#include <hip/hip_runtime.h>
#include <math.h>

#define MDIM 1024
#define TSEQ 2048
#define NSOL 5
#define DED  64
#define NBLK 3
#define KITER 4
#define XLDB 1088   // bf16 X leading dim: 1024 sp cols + 64 demb cols
#define NRED 6144   // 5120 P cols + 1024 mp cols
#define RST  64     // dirty-stage grid row stride

typedef __bf16 bf16x8 __attribute__((ext_vector_type(8)));
typedef __bf16 bf16x4 __attribute__((ext_vector_type(4)));
typedef float  f32x4  __attribute__((ext_vector_type(4)));

#define GLDS16(gptr, lptr) __builtin_amdgcn_global_load_lds( \
    (const __attribute__((address_space(1))) unsigned int*)(const void*)(gptr), \
    (__attribute__((address_space(3))) unsigned int*)(void*)(lptr), 16, 0, 0)

__device__ __forceinline__ float gelu_f(float x){
  return 0.5f * x * (1.0f + erff(x * 0.70710678118654752440f));
}
__device__ __forceinline__ float sigmoid_f(float x){ return 1.0f/(1.0f+expf(-x)); }
__device__ __forceinline__ float softplus_f(float x){ return fmaxf(x,0.0f) + log1pf(expf(-fabsf(x))); }

// ---------------- init speculative state ----------------
__global__ void k_init(float* prevg, int* dlist, int* dcnt){
  int i = blockIdx.x*blockDim.x + threadIdx.x;
  if (i < TSEQ){ prevg[i] = (i==0)? -1.0f : 1.0f; dlist[i] = i; }
  if (i == 0) *dcnt = TSEQ;
}

// ---------------- fused convert fp32 [K][N] -> bf16 transposed [N][K], 12 blocks of 4 srcs ----------------
__global__ __launch_bounds__(256) void k_cvtT12(const float* __restrict__ s0,
    const float* __restrict__ s1, const float* __restrict__ s2, const float* __restrict__ s3,
    __bf16* __restrict__ dst){
  __shared__ float t[32][33];
  const size_t MM = (size_t)MDIM*MDIM;
  int z = blockIdx.z;
  const float* s = (z<3)? s0 + (size_t)z*MM : (z<6)? s1 + (size_t)(z-3)*MM :
                   (z<9)? s2 + (size_t)(z-6)*MM : s3 + (size_t)(z-9)*MM;
  __bf16* d = dst + (size_t)z*MM;
  int k0 = blockIdx.y*32, n0 = blockIdx.x*32;
  int tx = threadIdx.x & 31, ty = threadIdx.x >> 5;
  #pragma unroll
  for (int r=0;r<32;r+=8) t[ty+r][tx] = s[(size_t)(k0+ty+r)*MDIM + n0+tx];
  __syncthreads();
  #pragma unroll
  for (int r=0;r<32;r+=8) d[(size_t)(n0+ty+r)*MDIM + k0+tx] = (__bf16)t[tx][ty+r];
}

// single-matrix version (for WpT, K=1088)
__global__ __launch_bounds__(256) void k_cvtT(const float* __restrict__ src,
                                              __bf16* __restrict__ dst, int K, int N){
  __shared__ float t[32][33];
  int k0 = blockIdx.y*32, n0 = blockIdx.x*32;
  int tx = threadIdx.x & 31, ty = threadIdx.x >> 5;
  #pragma unroll
  for (int r=0;r<32;r+=8) t[ty+r][tx] = src[(size_t)(k0+ty+r)*N + n0+tx];
  __syncthreads();
  #pragma unroll
  for (int r=0;r<32;r+=8) dst[(size_t)(n0+ty+r)*K + k0+tx] = (__bf16)t[tx][ty+r];
}

// ---------------- partial matvecs: P parts (solvent, y=0..4) + mol part (y=5) ----------------
__global__ __launch_bounds__(256) void k_pm(const float* __restrict__ sv,
    const float* __restrict__ spW, const float* __restrict__ mol,
    const float* __restrict__ bhw, float* __restrict__ PART){
  int s = blockIdx.y;
  int j = blockIdx.x*256 + threadIdx.x;
  int z = blockIdx.z, k0 = z*64;
  if (s < NSOL){
    const float* w = spW + (size_t)s*MDIM*MDIM + (size_t)k0*MDIM + j;
    const float* v = sv + s*MDIM + k0;
    float acc = 0.f;
    for (int k=0;k<64;k++) acc = fmaf(v[k], w[(size_t)k*MDIM], acc);
    PART[(size_t)z*NRED + s*MDIM + j] = acc;
  } else {
    const float* w = bhw + (size_t)k0*MDIM + j;
    float acc = 0.f;
    for (int k=0;k<64;k++) acc = fmaf(mol[k0+k], w[(size_t)k*MDIM], acc);
    PART[(size_t)z*NRED + 5120 + j] = acc;
  }
}

// ---------------- reduce partials -> P, mp(+bias) ----------------
__global__ __launch_bounds__(256) void k_red(const float* __restrict__ PART,
    const float* __restrict__ bhb, float* __restrict__ P, float* __restrict__ mp){
  int i = blockIdx.x*256 + threadIdx.x;
  float a = 0.f;
  #pragma unroll
  for (int z=0;z<16;z++) a += PART[(size_t)z*NRED + i];
  if (i < 5120) P[i] = a;
  else mp[i-5120] = a + bhb[i-5120];
}

// ---------------- fused sp0 + demb ----------------
__global__ __launch_bounds__(256) void k_sp0d(const float* __restrict__ ratios,
    const float* __restrict__ P, const float* __restrict__ bias,
    const float* __restrict__ desc, const float* __restrict__ dw,
    const float* __restrict__ db,
    float* __restrict__ X, __bf16* __restrict__ Xb){
  int t = blockIdx.y;
  if (blockIdx.x < 4){
    int j = blockIdx.x*256 + threadIdx.x;
    const float* r = ratios + t*NSOL;
    float acc = bias[j];
    #pragma unroll
    for (int s=0;s<NSOL;s++) acc = fmaf(r[s], P[s*MDIM+j], acc);
    float v = gelu_f(acc);
    X[(size_t)t*MDIM + j] = v;
    Xb[(size_t)t*XLDB + j] = (__bf16)v;
  } else if (threadIdx.x < DED){
    int e = threadIdx.x;
    const float* d = desc + t*6;
    float acc = db[e];
    #pragma unroll
    for (int c=0;c<6;c++) acc = fmaf(d[c], dw[c*DED+e], acc);
    Xb[(size_t)t*XLDB + MDIM + e] = (__bf16)gelu_f(acc);
  }
}

// ---------------- bf16 MFMA GEMM, glds + chunk-swizzle + 2-phase dbuf, 512 thr ----------------
// BM=128, BN=64, template BK. 8 waves (4r x 2c), each 32x32 = 2x2 16x16 frags.
template<int BK, bool GELU, bool RES, bool OUTF, bool OUTB, bool Z0>
__global__ __launch_bounds__(512) void k_mfma_gemm(
    const __bf16* __restrict__ A, int lda, int K,
    const __bf16* __restrict__ Bt,           // [N][K] bf16
    const float* __restrict__ bias,          // [N] fp32
    const float* __restrict__ R, int ldr,    // fp32 residual
    float* __restrict__ Cf, int ldcf,
    __bf16* __restrict__ Cb, int ldcb,
    const float* __restrict__ wlast, const float* __restrict__ prevg,
    float* __restrict__ Z0f, __bf16* __restrict__ Z0b)
{
  constexpr int CPR = BK/8;        // 16B chunks per row
  constexpr int AG  = BK/32;       // A stage groups per thread
  constexpr int BG  = (BK>=64)? BK/64 : 1;
  constexpr int KS  = BK/32;       // k-subtiles per tile
  __shared__ __attribute__((aligned(16))) __bf16 As[2][128*BK];
  __shared__ __attribute__((aligned(16))) __bf16 Bs[2][64*BK];
  int tid = threadIdx.x;
  int wave = tid>>6, lane = tid&63;
  int row0 = blockIdx.y*128, col0 = blockIdx.x*64;
  int wr = (wave>>1)*32, wc = (wave&1)*32;
  int lr = lane&15;
  f32x4 acc[2][2] = {};
  int NT = K / BK;

  auto stage = [&](int b, int k0){
    #pragma unroll
    for (int p=0;p<AG;p++){
      int q = wave*(AG*64) + p*64 + lane;      // A chunk id
      int r = q/CPR, c = q%CPR, cl = c^(r&7);
      GLDS16(A + (size_t)(row0+r)*lda + k0 + cl*8, &As[b][(wave*(AG*64)+p*64)*8]);
    }
    #pragma unroll
    for (int p=0;p<BG;p++){
      int q = wave*(BG*64) + p*64 + lane;      // B chunk id
      int r = q/CPR, c = q%CPR, cl = c^(r&7);
      GLDS16(Bt + (size_t)(col0+r)*K + k0 + cl*8, &Bs[b][(wave*(BG*64)+p*64)*8]);
    }
  };

  stage(0, 0);
  for (int t=0; t<NT; t++){
    __syncthreads();                           // drains stage(t) + protects buffer reuse
    if (t+1 < NT) stage((t+1)&1, (t+1)*BK);    // issue next tile's loads
    int b = t&1;
    #pragma unroll
    for (int ks=0;ks<KS;ks++){
      int c = ks*4 + (lane>>4);                // logical chunk = kk>>3
      bf16x8 af[2], bg[2];
      #pragma unroll
      for (int m=0;m<2;m++){
        int rowA = wr + m*16 + lr;
        af[m] = *(const bf16x8*)&As[b][rowA*BK + ((c ^ (rowA&7))<<3)];
      }
      #pragma unroll
      for (int n=0;n<2;n++){
        int rowB = wc + n*16 + lr;
        bg[n] = *(const bf16x8*)&Bs[b][rowB*BK + ((c ^ (rowB&7))<<3)];
      }
      #pragma unroll
      for (int m=0;m<2;m++)
        #pragma unroll
        for (int n=0;n<2;n++)
          acc[m][n] = __builtin_amdgcn_mfma_f32_16x16x32_bf16(af[m], bg[n], acc[m][n], 0,0,0);
    }
  }
  int rq = (lane>>4)*4;  // verified C/D layout: col = lane&15, row = (lane>>4)*4 + q
  #pragma unroll
  for (int m=0;m<2;m++){
    #pragma unroll
    for (int n=0;n<2;n++){
      int cc = col0 + wc + n*16 + lr;
      float bv = bias[cc];
      #pragma unroll
      for (int q=0;q<4;q++){
        int r = row0 + wr + m*16 + rq + q;
        float v = acc[m][n][q] + bv;
        if (RES)  v += R[(size_t)r*ldr + cc];
        if (GELU) v = gelu_f(v);
        if (OUTF) Cf[(size_t)r*ldcf + cc] = v;
        if (OUTB) Cb[(size_t)r*ldcb + cc] = (__bf16)v;
        if (Z0){
          float z = gelu_f(v + prevg[r]*wlast[cc]);
          Z0f[(size_t)r*MDIM + cc] = z;
          Z0b[(size_t)r*MDIM + cc] = (__bf16)z;
        }
      }
    }
  }
}

// ---------------- batched LayerNorm (float4) -> fp32 + bf16, optional fused mu/phi ----------------
template<bool MUPHI>
__global__ __launch_bounds__(256) void k_ln(const float* __restrict__ Y, int ldy,
    float* __restrict__ Xo, int ldx, __bf16* __restrict__ Xb, int ldxb,
    const float* __restrict__ g, const float* __restrict__ b,
    const float* __restrict__ muw, const float* __restrict__ mub,
    const float* __restrict__ phiw, const float* __restrict__ phib,
    float* __restrict__ muA, float* __restrict__ phiA)
{
  int t = blockIdx.x;
  __shared__ float red[16];
  int tid = threadIdx.x;
  f32x4 y = *(const f32x4*)&Y[(size_t)t*ldy + tid*4];
  float s  = y[0]+y[1]+y[2]+y[3];
  float s2 = y[0]*y[0]+y[1]*y[1]+y[2]*y[2]+y[3]*y[3];
  for (int o=32;o>0;o>>=1){ s += __shfl_down(s,o); s2 += __shfl_down(s2,o); }
  int wid = tid>>6, lane = tid&63;
  if (lane==0){ red[wid]=s; red[wid+8]=s2; }
  __syncthreads();
  if (tid==0){
    float a=0.f,c=0.f;
    for (int w=0;w<4;w++){ a+=red[w]; c+=red[w+8]; }
    red[0]=a; red[8]=c;
  }
  __syncthreads();
  float mean = red[0]*(1.0f/MDIM);
  float var  = red[8]*(1.0f/MDIM) - mean*mean;
  float rs = rsqrtf(var + 1e-5f);
  f32x4 gv = *(const f32x4*)&g[tid*4];
  f32x4 bb = *(const f32x4*)&b[tid*4];
  f32x4 v; bf16x4 vb;
  #pragma unroll
  for (int i=0;i<4;i++){ v[i] = gv[i]*(y[i]-mean)*rs + bb[i]; vb[i] = (__bf16)v[i]; }
  *(f32x4*)&Xo[(size_t)t*ldx + tid*4] = v;
  *(bf16x4*)&Xb[(size_t)t*ldxb + tid*4] = vb;
  if (MUPHI){
    f32x4 mw = *(const f32x4*)&muw[tid*4];
    f32x4 pw = *(const f32x4*)&phiw[tid*4];
    float sm=0.f, sp=0.f;
    #pragma unroll
    for (int i=0;i<4;i++){ sm = fmaf(v[i], mw[i], sm); sp = fmaf(v[i], pw[i], sp); }
    for (int o=32;o>0;o>>=1){ sm+=__shfl_down(sm,o); sp+=__shfl_down(sp,o); }
    __syncthreads();
    if (lane==0){ red[wid]=sm; red[wid+8]=sp; }
    __syncthreads();
    if (tid==0){
      float a=0.f,c=0.f;
      for (int w=0;w<4;w++){ a+=red[w]; c+=red[w+8]; }
      muA[t]  = sigmoid_f(a + mub[0]);
      phiA[t] = softplus_f(c + phib[0]) + 2.0f;
    }
  }
}

// ================= dirty-row refinement stages (staged, j-split — measured-good) =================

// fused z0 + fc1 (head block 0) for dirty rows
__global__ __launch_bounds__(256) void k_fc1z_dirty(
    const float* __restrict__ ZP, const float* __restrict__ wlast,
    const float* __restrict__ prevg,
    const __bf16* __restrict__ Wt, const float* __restrict__ bias,
    const int* __restrict__ dlist, const int* __restrict__ dcnt,
    float* __restrict__ Z, __bf16* __restrict__ Zb, __bf16* __restrict__ Ob)
{
  __shared__ __bf16 zl[MDIM];
  int nd = *dcnt;
  int jb = blockIdx.x;
  int j = jb*256 + threadIdx.x;
  for (int rs = blockIdx.y; rs < nd; rs += RST){
    int t = dlist[rs];
    float prev = prevg[t];
    #pragma unroll
    for (int q=0;q<4;q++){
      int k = threadIdx.x + 256*q;
      float v = gelu_f(ZP[(size_t)t*MDIM + k] + prev*wlast[k]);
      zl[k] = (__bf16)v;
      if (jb==0){ Z[(size_t)t*MDIM + k] = v; Zb[(size_t)t*MDIM + k] = (__bf16)v; }
    }
    __syncthreads();
    const __bf16* w = Wt + (size_t)j*MDIM;
    float acc = 0.f;
    for (int k=0;k<MDIM;k+=8){
      bf16x8 wv = *(const bf16x8*)&w[k];
      bf16x8 iv = *(const bf16x8*)&zl[k];
      #pragma unroll
      for (int u=0;u<8;u++) acc = fmaf((float)wv[u], (float)iv[u], acc);
    }
    acc = gelu_f(acc + bias[j]);
    Ob[(size_t)t*MDIM + j] = (__bf16)acc;
    __syncthreads();
  }
}

// fc matvec for dirty rows
template<bool GELU, bool RES, bool OUTB>
__global__ __launch_bounds__(256) void k_fc_dirty(
    const __bf16* __restrict__ In, const __bf16* __restrict__ Wt,
    const float* __restrict__ bias, const float* __restrict__ Rz,
    const int* __restrict__ dlist, const int* __restrict__ dcnt,
    __bf16* __restrict__ Ob, float* __restrict__ Of)
{
  int nd = *dcnt;
  int j = blockIdx.x*256 + threadIdx.x;
  for (int rs = blockIdx.y; rs < nd; rs += RST){
    int t = dlist[rs];
    const __bf16* in = In + (size_t)t*MDIM;
    const __bf16* w  = Wt + (size_t)j*MDIM;
    float acc = 0.f;
    for (int k=0;k<MDIM;k+=8){
      bf16x8 wv = *(const bf16x8*)&w[k];
      bf16x8 iv = *(const bf16x8*)&in[k];
      #pragma unroll
      for (int u=0;u<8;u++) acc = fmaf((float)wv[u], (float)iv[u], acc);
    }
    acc += bias[j];
    if (RES)  acc += Rz[(size_t)t*MDIM + j];
    if (GELU) acc = gelu_f(acc);
    if (OUTB) Ob[(size_t)t*MDIM + j] = (__bf16)acc;
    else      Of[(size_t)t*MDIM + j] = acc;
  }
}

// LayerNorm for dirty rows; optional fused mu/phi on final block
template<bool MUPHI>
__global__ __launch_bounds__(256) void k_ln_dirty(
    const float* __restrict__ Y,
    const float* __restrict__ g, const float* __restrict__ b,
    const int* __restrict__ dlist, const int* __restrict__ dcnt,
    float* __restrict__ Z, __bf16* __restrict__ Zb,
    const float* __restrict__ muw, const float* __restrict__ mub,
    const float* __restrict__ phiw, const float* __restrict__ phib,
    float* __restrict__ muA, float* __restrict__ phiA)
{
  int nd = *dcnt;
  __shared__ float red[16];
  int wid = threadIdx.x>>6, lane = threadIdx.x&63;
  for (int rs = blockIdx.x; rs < nd; rs += RST){
    int t = dlist[rs];
    float y[4]; float s=0.f, s2=0.f;
    #pragma unroll
    for (int q=0;q<4;q++){
      y[q] = Y[(size_t)t*MDIM + threadIdx.x + 256*q];
      s += y[q]; s2 += y[q]*y[q];
    }
    for (int o=32;o>0;o>>=1){ s += __shfl_down(s,o); s2 += __shfl_down(s2,o); }
    if (lane==0){ red[wid]=s; red[wid+8]=s2; }
    __syncthreads();
    if (threadIdx.x==0){
      float a=0.f,c=0.f;
      for (int w=0;w<4;w++){ a+=red[w]; c+=red[w+8]; }
      red[0]=a; red[8]=c;
    }
    __syncthreads();
    float mean = red[0]*(1.0f/MDIM);
    float var  = red[8]*(1.0f/MDIM) - mean*mean;
    float rs2 = rsqrtf(var + 1e-5f);
    float sm=0.f, sp=0.f;
    #pragma unroll
    for (int q=0;q<4;q++){
      int j = threadIdx.x + 256*q;
      float v = g[j]*(y[q]-mean)*rs2 + b[j];
      Z[(size_t)t*MDIM + j] = v;
      Zb[(size_t)t*MDIM + j] = (__bf16)v;
      if (MUPHI){ sm = fmaf(v, muw[j], sm); sp = fmaf(v, phiw[j], sp); }
    }
    __syncthreads();
    if (MUPHI){
      for (int o=32;o>0;o>>=1){ sm+=__shfl_down(sm,o); sp+=__shfl_down(sp,o); }
      if (lane==0){ red[wid]=sm; red[wid+8]=sp; }
      __syncthreads();
      if (threadIdx.x==0){
        float a=0.f,c=0.f;
        for (int w=0;w<4;w++){ a+=red[w]; c+=red[w+8]; }
        muA[t]  = sigmoid_f(a + mub[0]);
        phiA[t] = softplus_f(c + phib[0]) + 2.0f;
      }
      __syncthreads();
    }
  }
}

// ---------------- segmented prefix-product scan + dirty detection + output ----------------
__global__ __launch_bounds__(1024) void k_scan(
    const float* __restrict__ muA, const float* __restrict__ phiA,
    const unsigned char* __restrict__ bmask,
    float* __restrict__ prevg, int* __restrict__ dlist, int* __restrict__ dcnt,
    float* __restrict__ out)
{
  if (*dcnt == 0) return;   // converged: nothing changed since last scan
  __shared__ float v[2][TSEQ];
  __shared__ unsigned char f[2][TSEQ];
  __shared__ int cnt;
  int tid = threadIdx.x;
  if (tid==0) cnt = 0;
  for (int i=tid;i<TSEQ;i+=1024){
    v[0][i] = 1.0f - muA[i];
    f[0][i] = (i==0) || (bmask[i] != 0);
  }
  __syncthreads();
  int src=0;
  for (int off=1; off<TSEQ; off<<=1){
    int dst = src^1;
    for (int i=tid;i<TSEQ;i+=1024){
      float vv = v[src][i]; unsigned char ff = f[src][i];
      if (i>=off && !ff){ vv *= v[src][i-off]; ff = f[src][i-off]; }
      v[dst][i]=vv; f[dst][i]=ff;
    }
    __syncthreads();
    src = dst;
  }
  for (int i=tid;i<TSEQ;i+=1024){
    float rf = 1.0f - v[src][i];
    float prev = (i==0) ? -1.0f : (1.0f - v[src][i-1]);
    out[i]        = rf;
    out[TSEQ+i]   = muA[i];
    out[2*TSEQ+i] = phiA[i];
    float old = prevg[i];
    prevg[i] = prev;
    if (fabsf(prev - old) > 1e-3f){
      int pos = atomicAdd(&cnt, 1);
      dlist[pos] = i;
    }
  }
  __syncthreads();
  if (tid==0) *dcnt = cnt;
}

extern "C" void kernel_launch(void* const* d_in, const int* in_sizes, int n_in,
                              void* d_out, int out_size, void* d_ws, size_t ws_size,
                              hipStream_t stream) {
  const float* mol       = (const float*)d_in[0];
  const float* ratios    = (const float*)d_in[1];
  const float* desc      = (const float*)d_in[2];
  const float* svvec     = (const float*)d_in[3];
  const unsigned char* bmask = (const unsigned char*)d_in[4];
  const float* sp_proj_w = (const float*)d_in[5];
  const float* sp_proj_b = (const float*)d_in[6];
  const float* sp_fc1_w  = (const float*)d_in[7];
  const float* sp_fc1_b  = (const float*)d_in[8];
  const float* sp_fc2_w  = (const float*)d_in[9];
  const float* sp_fc2_b  = (const float*)d_in[10];
  const float* sp_ln_g   = (const float*)d_in[11];
  const float* sp_ln_b   = (const float*)d_in[12];
  const float* desc_w    = (const float*)d_in[13];
  const float* desc_b    = (const float*)d_in[14];
  const float* bh_proj_w = (const float*)d_in[15];
  const float* bh_proj_b = (const float*)d_in[16];
  const float* bh_fc1_w  = (const float*)d_in[17];
  const float* bh_fc1_b  = (const float*)d_in[18];
  const float* bh_fc2_w  = (const float*)d_in[19];
  const float* bh_fc2_b  = (const float*)d_in[20];
  const float* bh_ln_g   = (const float*)d_in[21];
  const float* bh_ln_b   = (const float*)d_in[22];
  const float* mu_w      = (const float*)d_in[23];
  const float* mu_b      = (const float*)d_in[24];
  const float* phi_w     = (const float*)d_in[25];
  const float* phi_b     = (const float*)d_in[26];
  float* out = (float*)d_out;

  char* p = (char*)d_ws;
  auto alloc = [&](size_t bytes)->char*{ char* r = p; p += (bytes + 255) & ~(size_t)255; return r; };
  const size_t MM = (size_t)MDIM*MDIM;
  float*  X    = (float*)alloc((size_t)TSEQ*MDIM*4);     // fp32 activations (sp x, later head z)
  __bf16* Xb   = (__bf16*)alloc((size_t)TSEQ*XLDB*2);    // bf16 [sp|demb]
  __bf16* Zb   = (__bf16*)alloc((size_t)TSEQ*MDIM*2);    // head bf16 z (separate: no alias w/ Xb)
  float*  Y    = (float*)alloc((size_t)TSEQ*MDIM*4);     // fp32 pre-LN
  float*  ZP   = (float*)alloc((size_t)TSEQ*MDIM*4);     // persistent head pre-activation
  __bf16* Hb16 = (__bf16*)alloc((size_t)TSEQ*MDIM*2);
  __bf16* WALL = (__bf16*)alloc(12*MM*2);                // W1T|W2T|U1T|U2T (3 blocks each)
  __bf16* WpT  = (__bf16*)alloc((size_t)MDIM*XLDB*2);    // [1024][1088]
  float*  PART = (float*)alloc((size_t)16*NRED*4);
  float*  P    = (float*)alloc((size_t)NSOL*MDIM*4);
  float*  mp   = (float*)alloc(MDIM*4);
  float*  prevg= (float*)alloc(TSEQ*4);
  float*  muA  = (float*)alloc(TSEQ*4);
  float*  phiA = (float*)alloc(TSEQ*4);
  int*    dlist= (int*)alloc(TSEQ*4);
  int*    dcnt = (int*)alloc(256);
  __bf16* W1T = WALL, *W2T = WALL + 3*MM, *U1T = WALL + 6*MM, *U2T = WALL + 9*MM;
  float*  Z    = X;      // alias: X fp32 dead after sp chain (zpre GEMM reads only Xb)

  k_init<<<dim3((TSEQ+255)/256),256,0,stream>>>(prevg, dlist, dcnt);
  k_cvtT12<<<dim3(32,32,12),256,0,stream>>>(sp_fc1_w, sp_fc2_w, bh_fc1_w, bh_fc2_w, WALL);
  k_cvtT<<<dim3(32,34,1),256,0,stream>>>(bh_proj_w + MM, WpT, XLDB, MDIM);

  k_pm<<<dim3(4,6,16),256,0,stream>>>(svvec, sp_proj_w, mol, bh_proj_w, PART);
  k_red<<<dim3(NRED/256),256,0,stream>>>(PART, bh_proj_b, P, mp);
  k_sp0d<<<dim3(5,TSEQ),256,0,stream>>>(ratios, P, sp_proj_b, desc, desc_w, desc_b, X, Xb);

  const float* wlast = bh_proj_w + (size_t)2112*MDIM;
  // sp residual chain (bf16 MFMA GEMMs, BK=128)
  for (int i=0;i<NBLK;i++){
    k_mfma_gemm<128,true,false,false,true,false><<<dim3(16,16),512,0,stream>>>(
        Xb, XLDB, MDIM, W1T + i*MM, sp_fc1_b + i*MDIM, nullptr, 0,
        nullptr, 0, Hb16, MDIM, nullptr, nullptr, nullptr, nullptr);
    k_mfma_gemm<128,false,true,true,false,false><<<dim3(16,16),512,0,stream>>>(
        Hb16, MDIM, MDIM, W2T + i*MM, sp_fc2_b + i*MDIM, X, MDIM,
        Y, MDIM, nullptr, 0, nullptr, nullptr, nullptr, nullptr);
    k_ln<false><<<dim3(TSEQ),256,0,stream>>>(Y, MDIM, X, MDIM, Xb, XLDB,
        sp_ln_g + i*MDIM, sp_ln_b + i*MDIM,
        nullptr, nullptr, nullptr, nullptr, nullptr, nullptr);
  }
  // z_pre GEMM (K=1088, BK=64) with fused z0 epilogue: ZP + speculative gelu -> Z/Zb
  k_mfma_gemm<64,false,false,true,false,true><<<dim3(16,16),512,0,stream>>>(
      Xb, XLDB, XLDB, WpT, mp, nullptr, 0, ZP, MDIM, nullptr, 0,
      wlast, prevg, Z, Zb);

  // ---- iteration 1: batched head with speculative prev ----
  for (int i=0;i<NBLK;i++){
    k_mfma_gemm<128,true,false,false,true,false><<<dim3(16,16),512,0,stream>>>(
        Zb, MDIM, MDIM, U1T + i*MM, bh_fc1_b + i*MDIM, nullptr, 0,
        nullptr, 0, Hb16, MDIM, nullptr, nullptr, nullptr, nullptr);
    k_mfma_gemm<128,false,true,true,false,false><<<dim3(16,16),512,0,stream>>>(
        Hb16, MDIM, MDIM, U2T + i*MM, bh_fc2_b + i*MDIM, Z, MDIM,
        Y, MDIM, nullptr, 0, nullptr, nullptr, nullptr, nullptr);
    if (i < NBLK-1)
      k_ln<false><<<dim3(TSEQ),256,0,stream>>>(Y, MDIM, Z, MDIM, Zb, MDIM,
          bh_ln_g + i*MDIM, bh_ln_b + i*MDIM,
          nullptr, nullptr, nullptr, nullptr, nullptr, nullptr);
    else
      k_ln<true><<<dim3(TSEQ),256,0,stream>>>(Y, MDIM, Z, MDIM, Zb, MDIM,
          bh_ln_g + i*MDIM, bh_ln_b + i*MDIM,
          mu_w, mu_b, phi_w, phi_b, muA, phiA);
  }
  k_scan<<<dim3(1),1024,0,stream>>>(muA, phiA, bmask, prevg, dlist, dcnt, out);

  // ---- refinement iterations: staged dirty-row head (j-split, measured-good) ----
  for (int it=1; it<KITER; it++){
    k_fc1z_dirty<<<dim3(4,RST),256,0,stream>>>(ZP, wlast, prevg,
        U1T, bh_fc1_b, dlist, dcnt, Z, Zb, Hb16);
    k_fc_dirty<false,true,false><<<dim3(4,RST),256,0,stream>>>(
        Hb16, U2T, bh_fc2_b, Z, dlist, dcnt, nullptr, Y);
    k_ln_dirty<false><<<dim3(RST),256,0,stream>>>(Y, bh_ln_g, bh_ln_b,
        dlist, dcnt, Z, Zb, nullptr, nullptr, nullptr, nullptr, nullptr, nullptr);
    for (int i=1;i<NBLK;i++){
      k_fc_dirty<true,false,true><<<dim3(4,RST),256,0,stream>>>(
          Zb, U1T + i*MM, bh_fc1_b + i*MDIM, nullptr, dlist, dcnt, Hb16, nullptr);
      k_fc_dirty<false,true,false><<<dim3(4,RST),256,0,stream>>>(
          Hb16, U2T + i*MM, bh_fc2_b + i*MDIM, Z, dlist, dcnt, nullptr, Y);
      if (i < NBLK-1)
        k_ln_dirty<false><<<dim3(RST),256,0,stream>>>(Y, bh_ln_g + i*MDIM, bh_ln_b + i*MDIM,
            dlist, dcnt, Z, Zb, nullptr, nullptr, nullptr, nullptr, nullptr, nullptr);
      else
        k_ln_dirty<true><<<dim3(RST),256,0,stream>>>(Y, bh_ln_g + i*MDIM, bh_ln_b + i*MDIM,
            dlist, dcnt, Z, Zb, mu_w, mu_b, phi_w, phi_b, muA, phiA);
    }
    k_scan<<<dim3(1),1024,0,stream>>>(muA, phiA, bmask, prevg, dlist, dcnt, out);
  }
  (void)in_sizes; (void)n_in; (void)out_size; (void)ws_size;
}

// Round 7
// 414.737 us; speedup vs baseline: 2.7924x; 1.0760x over previous
//
#include <hip/hip_runtime.h>
#include <math.h>

#define MDIM 1024
#define TSEQ 2048
#define NSOL 5
#define DED  64
#define NBLK 3
#define KITER 3
#define XLDB 1088   // bf16 X leading dim: 1024 sp cols + 64 demb cols
#define NRED 6144   // 5120 P cols + 1024 mp cols
#define RST  64     // dirty-stage grid row stride

typedef __bf16 bf16x8 __attribute__((ext_vector_type(8)));
typedef __bf16 bf16x4 __attribute__((ext_vector_type(4)));
typedef float  f32x4  __attribute__((ext_vector_type(4)));

#define GLDS16(gptr, lptr) __builtin_amdgcn_global_load_lds( \
    (const __attribute__((address_space(1))) unsigned int*)(const void*)(gptr), \
    (__attribute__((address_space(3))) unsigned int*)(void*)(lptr), 16, 0, 0)

__device__ __forceinline__ float gelu_f(float x){
  return 0.5f * x * (1.0f + erff(x * 0.70710678118654752440f));
}
__device__ __forceinline__ float sigmoid_f(float x){ return 1.0f/(1.0f+expf(-x)); }
__device__ __forceinline__ float softplus_f(float x){ return fmaxf(x,0.0f) + log1pf(expf(-fabsf(x))); }

// ---------------- fused convert fp32 -> bf16 transposed; z<12: [1024][1024]; z==12: WpT [1088][1024] ----------------
__global__ __launch_bounds__(256) void k_cvtT13(const float* __restrict__ s0,
    const float* __restrict__ s1, const float* __restrict__ s2, const float* __restrict__ s3,
    const float* __restrict__ s4, __bf16* __restrict__ dst, __bf16* __restrict__ WpT){
  __shared__ float t[32][33];
  const size_t MM = (size_t)MDIM*MDIM;
  int z = blockIdx.z;
  int tx = threadIdx.x & 31, ty = threadIdx.x >> 5;
  if (z < 12){
    if (blockIdx.y >= 32) return;
    const float* s = (z<3)? s0 + (size_t)z*MM : (z<6)? s1 + (size_t)(z-3)*MM :
                     (z<9)? s2 + (size_t)(z-6)*MM : s3 + (size_t)(z-9)*MM;
    __bf16* d = dst + (size_t)z*MM;
    int k0 = blockIdx.y*32, n0 = blockIdx.x*32;
    #pragma unroll
    for (int r=0;r<32;r+=8) t[ty+r][tx] = s[(size_t)(k0+ty+r)*MDIM + n0+tx];
    __syncthreads();
    #pragma unroll
    for (int r=0;r<32;r+=8) d[(size_t)(n0+ty+r)*MDIM + k0+tx] = (__bf16)t[tx][ty+r];
  } else {
    int k0 = blockIdx.y*32, n0 = blockIdx.x*32;   // K=1088 (34 y-blocks), N=1024
    #pragma unroll
    for (int r=0;r<32;r+=8) t[ty+r][tx] = s4[(size_t)(k0+ty+r)*MDIM + n0+tx];
    __syncthreads();
    #pragma unroll
    for (int r=0;r<32;r+=8) WpT[(size_t)(n0+ty+r)*XLDB + k0+tx] = (__bf16)t[tx][ty+r];
  }
}

// ---------------- partial matvecs: P parts (solvent, y=0..4) + mol part (y=5) ----------------
__global__ __launch_bounds__(256) void k_pm(const float* __restrict__ sv,
    const float* __restrict__ spW, const float* __restrict__ mol,
    const float* __restrict__ bhw, float* __restrict__ PART){
  int s = blockIdx.y;
  int j = blockIdx.x*256 + threadIdx.x;
  int z = blockIdx.z, k0 = z*64;
  if (s < NSOL){
    const float* w = spW + (size_t)s*MDIM*MDIM + (size_t)k0*MDIM + j;
    const float* v = sv + s*MDIM + k0;
    float acc = 0.f;
    for (int k=0;k<64;k++) acc = fmaf(v[k], w[(size_t)k*MDIM], acc);
    PART[(size_t)z*NRED + s*MDIM + j] = acc;
  } else {
    const float* w = bhw + (size_t)k0*MDIM + j;
    float acc = 0.f;
    for (int k=0;k<64;k++) acc = fmaf(mol[k0+k], w[(size_t)k*MDIM], acc);
    PART[(size_t)z*NRED + 5120 + j] = acc;
  }
}

// ---------------- reduce partials -> P, mp(+bias); also init speculative state ----------------
__global__ __launch_bounds__(256) void k_red(const float* __restrict__ PART,
    const float* __restrict__ bhb, float* __restrict__ P, float* __restrict__ mp,
    float* __restrict__ prevg, int* __restrict__ dlist, int* __restrict__ dcnt){
  int i = blockIdx.x*256 + threadIdx.x;
  if (i < TSEQ){ prevg[i] = (i==0)? -1.0f : 1.0f; dlist[i] = i; }
  if (i == 0) *dcnt = TSEQ;
  float a = 0.f;
  #pragma unroll
  for (int z=0;z<16;z++) a += PART[(size_t)z*NRED + i];
  if (i < 5120) P[i] = a;
  else mp[i-5120] = a + bhb[i-5120];
}

// ---------------- fused sp0 + demb ----------------
__global__ __launch_bounds__(256) void k_sp0d(const float* __restrict__ ratios,
    const float* __restrict__ P, const float* __restrict__ bias,
    const float* __restrict__ desc, const float* __restrict__ dw,
    const float* __restrict__ db,
    float* __restrict__ X, __bf16* __restrict__ Xb){
  int t = blockIdx.y;
  if (blockIdx.x < 4){
    int j = blockIdx.x*256 + threadIdx.x;
    const float* r = ratios + t*NSOL;
    float acc = bias[j];
    #pragma unroll
    for (int s=0;s<NSOL;s++) acc = fmaf(r[s], P[s*MDIM+j], acc);
    float v = gelu_f(acc);
    X[(size_t)t*MDIM + j] = v;
    Xb[(size_t)t*XLDB + j] = (__bf16)v;
  } else if (threadIdx.x < DED){
    int e = threadIdx.x;
    const float* d = desc + t*6;
    float acc = db[e];
    #pragma unroll
    for (int c=0;c<6;c++) acc = fmaf(d[c], dw[c*DED+e], acc);
    Xb[(size_t)t*XLDB + MDIM + e] = (__bf16)gelu_f(acc);
  }
}

// ---------------- bf16 MFMA GEMM, glds + chunk-swizzle + 2-phase dbuf, 512 thr ----------------
// BM=128, BN=64, template BK. 8 waves (4r x 2c), each 32x32 = 2x2 16x16 frags.
template<int BK, bool GELU, bool RES, bool OUTF, bool OUTB, bool Z0>
__global__ __launch_bounds__(512) void k_mfma_gemm(
    const __bf16* __restrict__ A, int lda, int K,
    const __bf16* __restrict__ Bt,           // [N][K] bf16
    const float* __restrict__ bias,          // [N] fp32
    const float* __restrict__ R, int ldr,    // fp32 residual
    float* __restrict__ Cf, int ldcf,
    __bf16* __restrict__ Cb, int ldcb,
    const float* __restrict__ wlast, const float* __restrict__ prevg,
    float* __restrict__ Z0f, __bf16* __restrict__ Z0b)
{
  constexpr int CPR = BK/8;        // 16B chunks per row
  constexpr int AG  = BK/32;       // A stage groups per thread
  constexpr int BG  = (BK>=64)? BK/64 : 1;
  constexpr int KS  = BK/32;       // k-subtiles per tile
  __shared__ __attribute__((aligned(16))) __bf16 As[2][128*BK];
  __shared__ __attribute__((aligned(16))) __bf16 Bs[2][64*BK];
  int tid = threadIdx.x;
  int wave = tid>>6, lane = tid&63;
  int row0 = blockIdx.y*128, col0 = blockIdx.x*64;
  int wr = (wave>>1)*32, wc = (wave&1)*32;
  int lr = lane&15;
  f32x4 acc[2][2] = {};
  int NT = K / BK;

  auto stage = [&](int b, int k0){
    #pragma unroll
    for (int p=0;p<AG;p++){
      int q = wave*(AG*64) + p*64 + lane;      // A chunk id
      int r = q/CPR, c = q%CPR, cl = c^(r&7);
      GLDS16(A + (size_t)(row0+r)*lda + k0 + cl*8, &As[b][(wave*(AG*64)+p*64)*8]);
    }
    #pragma unroll
    for (int p=0;p<BG;p++){
      int q = wave*(BG*64) + p*64 + lane;      // B chunk id
      int r = q/CPR, c = q%CPR, cl = c^(r&7);
      GLDS16(Bt + (size_t)(col0+r)*K + k0 + cl*8, &Bs[b][(wave*(BG*64)+p*64)*8]);
    }
  };

  stage(0, 0);
  for (int t=0; t<NT; t++){
    __syncthreads();                           // drains stage(t) + protects buffer reuse
    if (t+1 < NT) stage((t+1)&1, (t+1)*BK);    // issue next tile's loads
    int b = t&1;
    #pragma unroll
    for (int ks=0;ks<KS;ks++){
      int c = ks*4 + (lane>>4);                // logical chunk = kk>>3
      bf16x8 af[2], bg[2];
      #pragma unroll
      for (int m=0;m<2;m++){
        int rowA = wr + m*16 + lr;
        af[m] = *(const bf16x8*)&As[b][rowA*BK + ((c ^ (rowA&7))<<3)];
      }
      #pragma unroll
      for (int n=0;n<2;n++){
        int rowB = wc + n*16 + lr;
        bg[n] = *(const bf16x8*)&Bs[b][rowB*BK + ((c ^ (rowB&7))<<3)];
      }
      #pragma unroll
      for (int m=0;m<2;m++)
        #pragma unroll
        for (int n=0;n<2;n++)
          acc[m][n] = __builtin_amdgcn_mfma_f32_16x16x32_bf16(af[m], bg[n], acc[m][n], 0,0,0);
    }
  }
  int rq = (lane>>4)*4;  // verified C/D layout: col = lane&15, row = (lane>>4)*4 + q
  #pragma unroll
  for (int m=0;m<2;m++){
    #pragma unroll
    for (int n=0;n<2;n++){
      int cc = col0 + wc + n*16 + lr;
      float bv = bias[cc];
      #pragma unroll
      for (int q=0;q<4;q++){
        int r = row0 + wr + m*16 + rq + q;
        float v = acc[m][n][q] + bv;
        if (RES)  v += R[(size_t)r*ldr + cc];
        if (GELU) v = gelu_f(v);
        if (OUTF) Cf[(size_t)r*ldcf + cc] = v;
        if (OUTB) Cb[(size_t)r*ldcb + cc] = (__bf16)v;
        if (Z0){
          float z = gelu_f(v + prevg[r]*wlast[cc]);
          Z0f[(size_t)r*MDIM + cc] = z;
          Z0b[(size_t)r*MDIM + cc] = (__bf16)z;
        }
      }
    }
  }
}

// ---------------- batched LayerNorm (float4) -> fp32 + bf16, optional fused mu/phi ----------------
template<bool MUPHI>
__global__ __launch_bounds__(256) void k_ln(const float* __restrict__ Y, int ldy,
    float* __restrict__ Xo, int ldx, __bf16* __restrict__ Xb, int ldxb,
    const float* __restrict__ g, const float* __restrict__ b,
    const float* __restrict__ muw, const float* __restrict__ mub,
    const float* __restrict__ phiw, const float* __restrict__ phib,
    float* __restrict__ muA, float* __restrict__ phiA)
{
  int t = blockIdx.x;
  __shared__ float red[16];
  int tid = threadIdx.x;
  f32x4 y = *(const f32x4*)&Y[(size_t)t*ldy + tid*4];
  float s  = y[0]+y[1]+y[2]+y[3];
  float s2 = y[0]*y[0]+y[1]*y[1]+y[2]*y[2]+y[3]*y[3];
  for (int o=32;o>0;o>>=1){ s += __shfl_down(s,o); s2 += __shfl_down(s2,o); }
  int wid = tid>>6, lane = tid&63;
  if (lane==0){ red[wid]=s; red[wid+8]=s2; }
  __syncthreads();
  if (tid==0){
    float a=0.f,c=0.f;
    for (int w=0;w<4;w++){ a+=red[w]; c+=red[w+8]; }
    red[0]=a; red[8]=c;
  }
  __syncthreads();
  float mean = red[0]*(1.0f/MDIM);
  float var  = red[8]*(1.0f/MDIM) - mean*mean;
  float rs = rsqrtf(var + 1e-5f);
  f32x4 gv = *(const f32x4*)&g[tid*4];
  f32x4 bb = *(const f32x4*)&b[tid*4];
  f32x4 v; bf16x4 vb;
  #pragma unroll
  for (int i=0;i<4;i++){ v[i] = gv[i]*(y[i]-mean)*rs + bb[i]; vb[i] = (__bf16)v[i]; }
  *(f32x4*)&Xo[(size_t)t*ldx + tid*4] = v;
  *(bf16x4*)&Xb[(size_t)t*ldxb + tid*4] = vb;
  if (MUPHI){
    f32x4 mw = *(const f32x4*)&muw[tid*4];
    f32x4 pw = *(const f32x4*)&phiw[tid*4];
    float sm=0.f, sp=0.f;
    #pragma unroll
    for (int i=0;i<4;i++){ sm = fmaf(v[i], mw[i], sm); sp = fmaf(v[i], pw[i], sp); }
    for (int o=32;o>0;o>>=1){ sm+=__shfl_down(sm,o); sp+=__shfl_down(sp,o); }
    __syncthreads();
    if (lane==0){ red[wid]=sm; red[wid+8]=sp; }
    __syncthreads();
    if (tid==0){
      float a=0.f,c=0.f;
      for (int w=0;w<4;w++){ a+=red[w]; c+=red[w+8]; }
      muA[t]  = sigmoid_f(a + mub[0]);
      phiA[t] = softplus_f(c + phib[0]) + 2.0f;
    }
  }
}

// ================= dirty-row refinement stages (staged, j-split — measured-good) =================

// fused z0 + fc1 (head block 0) for dirty rows
__global__ __launch_bounds__(256) void k_fc1z_dirty(
    const float* __restrict__ ZP, const float* __restrict__ wlast,
    const float* __restrict__ prevg,
    const __bf16* __restrict__ Wt, const float* __restrict__ bias,
    const int* __restrict__ dlist, const int* __restrict__ dcnt,
    float* __restrict__ Z, __bf16* __restrict__ Zb, __bf16* __restrict__ Ob)
{
  __shared__ __bf16 zl[MDIM];
  int nd = *dcnt;
  int jb = blockIdx.x;
  int j = jb*256 + threadIdx.x;
  for (int rs = blockIdx.y; rs < nd; rs += RST){
    int t = dlist[rs];
    float prev = prevg[t];
    #pragma unroll
    for (int q=0;q<4;q++){
      int k = threadIdx.x + 256*q;
      float v = gelu_f(ZP[(size_t)t*MDIM + k] + prev*wlast[k]);
      zl[k] = (__bf16)v;
      if (jb==0){ Z[(size_t)t*MDIM + k] = v; Zb[(size_t)t*MDIM + k] = (__bf16)v; }
    }
    __syncthreads();
    const __bf16* w = Wt + (size_t)j*MDIM;
    float acc = 0.f;
    for (int k=0;k<MDIM;k+=8){
      bf16x8 wv = *(const bf16x8*)&w[k];
      bf16x8 iv = *(const bf16x8*)&zl[k];
      #pragma unroll
      for (int u=0;u<8;u++) acc = fmaf((float)wv[u], (float)iv[u], acc);
    }
    acc = gelu_f(acc + bias[j]);
    Ob[(size_t)t*MDIM + j] = (__bf16)acc;
    __syncthreads();
  }
}

// fc matvec for dirty rows (fc2 + residual -> Y fp32)
__global__ __launch_bounds__(256) void k_fc2_dirty(
    const __bf16* __restrict__ In, const __bf16* __restrict__ Wt,
    const float* __restrict__ bias, const float* __restrict__ Rz,
    const int* __restrict__ dlist, const int* __restrict__ dcnt,
    float* __restrict__ Of)
{
  int nd = *dcnt;
  int j = blockIdx.x*256 + threadIdx.x;
  for (int rs = blockIdx.y; rs < nd; rs += RST){
    int t = dlist[rs];
    const __bf16* in = In + (size_t)t*MDIM;
    const __bf16* w  = Wt + (size_t)j*MDIM;
    float acc = 0.f;
    for (int k=0;k<MDIM;k+=8){
      bf16x8 wv = *(const bf16x8*)&w[k];
      bf16x8 iv = *(const bf16x8*)&in[k];
      #pragma unroll
      for (int u=0;u<8;u++) acc = fmaf((float)wv[u], (float)iv[u], acc);
    }
    Of[(size_t)t*MDIM + j] = acc + bias[j] + Rz[(size_t)t*MDIM + j];
  }
}

// fused LN (of Y) + fc1 matvec for dirty rows: per block, LN full row -> LDS, then j-slice matvec
__global__ __launch_bounds__(256) void k_lnfc1_dirty(
    const float* __restrict__ Y,
    const float* __restrict__ g, const float* __restrict__ b,
    const __bf16* __restrict__ Wt, const float* __restrict__ fbias,
    const int* __restrict__ dlist, const int* __restrict__ dcnt,
    float* __restrict__ Z, __bf16* __restrict__ Zb, __bf16* __restrict__ Ob)
{
  __shared__ __bf16 zl[MDIM];
  __shared__ float red[16];
  int nd = *dcnt;
  int jb = blockIdx.x;
  int j = jb*256 + threadIdx.x;
  int wid = threadIdx.x>>6, lane = threadIdx.x&63;
  for (int rs = blockIdx.y; rs < nd; rs += RST){
    int t = dlist[rs];
    float y[4]; float s=0.f, s2=0.f;
    #pragma unroll
    for (int q=0;q<4;q++){
      y[q] = Y[(size_t)t*MDIM + threadIdx.x + 256*q];
      s += y[q]; s2 += y[q]*y[q];
    }
    for (int o=32;o>0;o>>=1){ s += __shfl_down(s,o); s2 += __shfl_down(s2,o); }
    if (lane==0){ red[wid]=s; red[wid+8]=s2; }
    __syncthreads();
    if (threadIdx.x==0){
      float a=0.f,c=0.f;
      for (int w=0;w<4;w++){ a+=red[w]; c+=red[w+8]; }
      red[0]=a; red[8]=c;
    }
    __syncthreads();
    float mean = red[0]*(1.0f/MDIM);
    float var  = red[8]*(1.0f/MDIM) - mean*mean;
    float rs2 = rsqrtf(var + 1e-5f);
    #pragma unroll
    for (int q=0;q<4;q++){
      int k = threadIdx.x + 256*q;
      float v = g[k]*(y[q]-mean)*rs2 + b[k];
      zl[k] = (__bf16)v;
      if (jb==0){ Z[(size_t)t*MDIM + k] = v; Zb[(size_t)t*MDIM + k] = (__bf16)v; }
    }
    __syncthreads();
    const __bf16* w = Wt + (size_t)j*MDIM;
    float acc = 0.f;
    for (int k=0;k<MDIM;k+=8){
      bf16x8 wv = *(const bf16x8*)&w[k];
      bf16x8 iv = *(const bf16x8*)&zl[k];
      #pragma unroll
      for (int u=0;u<8;u++) acc = fmaf((float)wv[u], (float)iv[u], acc);
    }
    acc = gelu_f(acc + fbias[j]);
    Ob[(size_t)t*MDIM + j] = (__bf16)acc;
    __syncthreads();
  }
}

// LayerNorm for dirty rows with fused mu/phi (final block)
__global__ __launch_bounds__(256) void k_lnmp_dirty(
    const float* __restrict__ Y,
    const float* __restrict__ g, const float* __restrict__ b,
    const int* __restrict__ dlist, const int* __restrict__ dcnt,
    const float* __restrict__ muw, const float* __restrict__ mub,
    const float* __restrict__ phiw, const float* __restrict__ phib,
    float* __restrict__ muA, float* __restrict__ phiA)
{
  int nd = *dcnt;
  __shared__ float red[16];
  int wid = threadIdx.x>>6, lane = threadIdx.x&63;
  for (int rs = blockIdx.x; rs < nd; rs += RST){
    int t = dlist[rs];
    float y[4]; float s=0.f, s2=0.f;
    #pragma unroll
    for (int q=0;q<4;q++){
      y[q] = Y[(size_t)t*MDIM + threadIdx.x + 256*q];
      s += y[q]; s2 += y[q]*y[q];
    }
    for (int o=32;o>0;o>>=1){ s += __shfl_down(s,o); s2 += __shfl_down(s2,o); }
    if (lane==0){ red[wid]=s; red[wid+8]=s2; }
    __syncthreads();
    if (threadIdx.x==0){
      float a=0.f,c=0.f;
      for (int w=0;w<4;w++){ a+=red[w]; c+=red[w+8]; }
      red[0]=a; red[8]=c;
    }
    __syncthreads();
    float mean = red[0]*(1.0f/MDIM);
    float var  = red[8]*(1.0f/MDIM) - mean*mean;
    float rs2 = rsqrtf(var + 1e-5f);
    float sm=0.f, sp=0.f;
    #pragma unroll
    for (int q=0;q<4;q++){
      int k = threadIdx.x + 256*q;
      float v = g[k]*(y[q]-mean)*rs2 + b[k];
      sm = fmaf(v, muw[k], sm); sp = fmaf(v, phiw[k], sp);
    }
    __syncthreads();
    for (int o=32;o>0;o>>=1){ sm+=__shfl_down(sm,o); sp+=__shfl_down(sp,o); }
    if (lane==0){ red[wid]=sm; red[wid+8]=sp; }
    __syncthreads();
    if (threadIdx.x==0){
      float a=0.f,c=0.f;
      for (int w=0;w<4;w++){ a+=red[w]; c+=red[w+8]; }
      muA[t]  = sigmoid_f(a + mub[0]);
      phiA[t] = softplus_f(c + phib[0]) + 2.0f;
    }
    __syncthreads();
  }
}

// ---------------- segmented prefix-product scan + dirty detection + output ----------------
__global__ __launch_bounds__(1024) void k_scan(
    const float* __restrict__ muA, const float* __restrict__ phiA,
    const unsigned char* __restrict__ bmask,
    float* __restrict__ prevg, int* __restrict__ dlist, int* __restrict__ dcnt,
    float* __restrict__ out)
{
  if (*dcnt == 0) return;   // converged: nothing changed since last scan
  __shared__ float v[2][TSEQ];
  __shared__ unsigned char f[2][TSEQ];
  __shared__ int cnt;
  int tid = threadIdx.x;
  if (tid==0) cnt = 0;
  for (int i=tid;i<TSEQ;i+=1024){
    v[0][i] = 1.0f - muA[i];
    f[0][i] = (i==0) || (bmask[i] != 0);
  }
  __syncthreads();
  int src=0;
  for (int off=1; off<TSEQ; off<<=1){
    int dst = src^1;
    for (int i=tid;i<TSEQ;i+=1024){
      float vv = v[src][i]; unsigned char ff = f[src][i];
      if (i>=off && !ff){ vv *= v[src][i-off]; ff = f[src][i-off]; }
      v[dst][i]=vv; f[dst][i]=ff;
    }
    __syncthreads();
    src = dst;
  }
  for (int i=tid;i<TSEQ;i+=1024){
    float rf = 1.0f - v[src][i];
    float prev = (i==0) ? -1.0f : (1.0f - v[src][i-1]);
    out[i]        = rf;
    out[TSEQ+i]   = muA[i];
    out[2*TSEQ+i] = phiA[i];
    float old = prevg[i];
    prevg[i] = prev;
    if (fabsf(prev - old) > 1e-3f){
      int pos = atomicAdd(&cnt, 1);
      dlist[pos] = i;
    }
  }
  __syncthreads();
  if (tid==0) *dcnt = cnt;
}

extern "C" void kernel_launch(void* const* d_in, const int* in_sizes, int n_in,
                              void* d_out, int out_size, void* d_ws, size_t ws_size,
                              hipStream_t stream) {
  const float* mol       = (const float*)d_in[0];
  const float* ratios    = (const float*)d_in[1];
  const float* desc      = (const float*)d_in[2];
  const float* svvec     = (const float*)d_in[3];
  const unsigned char* bmask = (const unsigned char*)d_in[4];
  const float* sp_proj_w = (const float*)d_in[5];
  const float* sp_proj_b = (const float*)d_in[6];
  const float* sp_fc1_w  = (const float*)d_in[7];
  const float* sp_fc1_b  = (const float*)d_in[8];
  const float* sp_fc2_w  = (const float*)d_in[9];
  const float* sp_fc2_b  = (const float*)d_in[10];
  const float* sp_ln_g   = (const float*)d_in[11];
  const float* sp_ln_b   = (const float*)d_in[12];
  const float* desc_w    = (const float*)d_in[13];
  const float* desc_b    = (const float*)d_in[14];
  const float* bh_proj_w = (const float*)d_in[15];
  const float* bh_proj_b = (const float*)d_in[16];
  const float* bh_fc1_w  = (const float*)d_in[17];
  const float* bh_fc1_b  = (const float*)d_in[18];
  const float* bh_fc2_w  = (const float*)d_in[19];
  const float* bh_fc2_b  = (const float*)d_in[20];
  const float* bh_ln_g   = (const float*)d_in[21];
  const float* bh_ln_b   = (const float*)d_in[22];
  const float* mu_w      = (const float*)d_in[23];
  const float* mu_b      = (const float*)d_in[24];
  const float* phi_w     = (const float*)d_in[25];
  const float* phi_b     = (const float*)d_in[26];
  float* out = (float*)d_out;

  char* p = (char*)d_ws;
  auto alloc = [&](size_t bytes)->char*{ char* r = p; p += (bytes + 255) & ~(size_t)255; return r; };
  const size_t MM = (size_t)MDIM*MDIM;
  float*  X    = (float*)alloc((size_t)TSEQ*MDIM*4);     // fp32 activations (sp x, later head z)
  __bf16* Xb   = (__bf16*)alloc((size_t)TSEQ*XLDB*2);    // bf16 [sp|demb]
  __bf16* Zb   = (__bf16*)alloc((size_t)TSEQ*MDIM*2);    // head bf16 z
  float*  Y    = (float*)alloc((size_t)TSEQ*MDIM*4);     // fp32 pre-LN
  float*  ZP   = (float*)alloc((size_t)TSEQ*MDIM*4);     // persistent head pre-activation
  __bf16* Hb16 = (__bf16*)alloc((size_t)TSEQ*MDIM*2);
  __bf16* WALL = (__bf16*)alloc(12*MM*2);                // W1T|W2T|U1T|U2T (3 blocks each)
  __bf16* WpT  = (__bf16*)alloc((size_t)MDIM*XLDB*2);    // [1024][1088]
  float*  PART = (float*)alloc((size_t)16*NRED*4);
  float*  P    = (float*)alloc((size_t)NSOL*MDIM*4);
  float*  mp   = (float*)alloc(MDIM*4);
  float*  prevg= (float*)alloc(TSEQ*4);
  float*  muA  = (float*)alloc(TSEQ*4);
  float*  phiA = (float*)alloc(TSEQ*4);
  int*    dlist= (int*)alloc(TSEQ*4);
  int*    dcnt = (int*)alloc(256);
  __bf16* W1T = WALL, *W2T = WALL + 3*MM, *U1T = WALL + 6*MM, *U2T = WALL + 9*MM;
  float*  Z    = X;      // alias: X fp32 dead after sp chain (zpre GEMM reads only Xb)

  k_cvtT13<<<dim3(32,34,13),256,0,stream>>>(sp_fc1_w, sp_fc2_w, bh_fc1_w, bh_fc2_w,
      bh_proj_w + MM, WALL, WpT);
  k_pm<<<dim3(4,6,16),256,0,stream>>>(svvec, sp_proj_w, mol, bh_proj_w, PART);
  k_red<<<dim3(NRED/256),256,0,stream>>>(PART, bh_proj_b, P, mp, prevg, dlist, dcnt);
  k_sp0d<<<dim3(5,TSEQ),256,0,stream>>>(ratios, P, sp_proj_b, desc, desc_w, desc_b, X, Xb);

  const float* wlast = bh_proj_w + (size_t)2112*MDIM;
  // sp residual chain (bf16 MFMA GEMMs, BK=128)
  for (int i=0;i<NBLK;i++){
    k_mfma_gemm<128,true,false,false,true,false><<<dim3(16,16),512,0,stream>>>(
        Xb, XLDB, MDIM, W1T + i*MM, sp_fc1_b + i*MDIM, nullptr, 0,
        nullptr, 0, Hb16, MDIM, nullptr, nullptr, nullptr, nullptr);
    k_mfma_gemm<128,false,true,true,false,false><<<dim3(16,16),512,0,stream>>>(
        Hb16, MDIM, MDIM, W2T + i*MM, sp_fc2_b + i*MDIM, X, MDIM,
        Y, MDIM, nullptr, 0, nullptr, nullptr, nullptr, nullptr);
    k_ln<false><<<dim3(TSEQ),256,0,stream>>>(Y, MDIM, X, MDIM, Xb, XLDB,
        sp_ln_g + i*MDIM, sp_ln_b + i*MDIM,
        nullptr, nullptr, nullptr, nullptr, nullptr, nullptr);
  }
  // z_pre GEMM (K=1088, BK=64) with fused z0 epilogue: ZP + speculative gelu -> Z/Zb
  k_mfma_gemm<64,false,false,true,false,true><<<dim3(16,16),512,0,stream>>>(
      Xb, XLDB, XLDB, WpT, mp, nullptr, 0, ZP, MDIM, nullptr, 0,
      wlast, prevg, Z, Zb);

  // ---- iteration 1: batched head with speculative prev ----
  for (int i=0;i<NBLK;i++){
    k_mfma_gemm<128,true,false,false,true,false><<<dim3(16,16),512,0,stream>>>(
        Zb, MDIM, MDIM, U1T + i*MM, bh_fc1_b + i*MDIM, nullptr, 0,
        nullptr, 0, Hb16, MDIM, nullptr, nullptr, nullptr, nullptr);
    k_mfma_gemm<128,false,true,true,false,false><<<dim3(16,16),512,0,stream>>>(
        Hb16, MDIM, MDIM, U2T + i*MM, bh_fc2_b + i*MDIM, Z, MDIM,
        Y, MDIM, nullptr, 0, nullptr, nullptr, nullptr, nullptr);
    if (i < NBLK-1)
      k_ln<false><<<dim3(TSEQ),256,0,stream>>>(Y, MDIM, Z, MDIM, Zb, MDIM,
          bh_ln_g + i*MDIM, bh_ln_b + i*MDIM,
          nullptr, nullptr, nullptr, nullptr, nullptr, nullptr);
    else
      k_ln<true><<<dim3(TSEQ),256,0,stream>>>(Y, MDIM, Z, MDIM, Zb, MDIM,
          bh_ln_g + i*MDIM, bh_ln_b + i*MDIM,
          mu_w, mu_b, phi_w, phi_b, muA, phiA);
  }
  k_scan<<<dim3(1),1024,0,stream>>>(muA, phiA, bmask, prevg, dlist, dcnt, out);

  // ---- refinement iterations: staged dirty-row head (8 launches/iter) ----
  for (int it=1; it<KITER; it++){
    k_fc1z_dirty<<<dim3(4,RST),256,0,stream>>>(ZP, wlast, prevg,
        U1T, bh_fc1_b, dlist, dcnt, Z, Zb, Hb16);
    k_fc2_dirty<<<dim3(4,RST),256,0,stream>>>(
        Hb16, U2T, bh_fc2_b, Z, dlist, dcnt, Y);
    for (int i=1;i<NBLK;i++){
      k_lnfc1_dirty<<<dim3(4,RST),256,0,stream>>>(Y,
          bh_ln_g + (i-1)*MDIM, bh_ln_b + (i-1)*MDIM,
          U1T + i*MM, bh_fc1_b + i*MDIM, dlist, dcnt, Z, Zb, Hb16);
      k_fc2_dirty<<<dim3(4,RST),256,0,stream>>>(
          Hb16, U2T + i*MM, bh_fc2_b + i*MDIM, Z, dlist, dcnt, Y);
    }
    k_lnmp_dirty<<<dim3(RST),256,0,stream>>>(Y,
        bh_ln_g + (NBLK-1)*MDIM, bh_ln_b + (NBLK-1)*MDIM,
        dlist, dcnt, mu_w, mu_b, phi_w, phi_b, muA, phiA);
    k_scan<<<dim3(1),1024,0,stream>>>(muA, phiA, bmask, prevg, dlist, dcnt, out);
  }
  (void)in_sizes; (void)n_in; (void)out_size; (void)ws_size;
}

// Round 8
// 384.389 us; speedup vs baseline: 3.0129x; 1.0790x over previous
//
#include <hip/hip_runtime.h>
#include <math.h>

#define MDIM 1024
#define TSEQ 2048
#define NSOL 5
#define DED  64
#define NBLK 3
#define KITER 3
#define XLDB 1088   // bf16 X leading dim: 1024 sp cols + 64 demb cols
#define NRED 6144   // 5120 P cols + 1024 mp cols
#define RST  64     // dirty-stage grid row stride

typedef __bf16 bf16x8 __attribute__((ext_vector_type(8)));
typedef __bf16 bf16x4 __attribute__((ext_vector_type(4)));
typedef float  f32x4  __attribute__((ext_vector_type(4)));

#define GLDS16(gptr, lptr) __builtin_amdgcn_global_load_lds( \
    (const __attribute__((address_space(1))) unsigned int*)(const void*)(gptr), \
    (__attribute__((address_space(3))) unsigned int*)(void*)(lptr), 16, 0, 0)

__device__ __forceinline__ float gelu_f(float x){
  return 0.5f * x * (1.0f + erff(x * 0.70710678118654752440f));
}
__device__ __forceinline__ float sigmoid_f(float x){ return 1.0f/(1.0f+expf(-x)); }
__device__ __forceinline__ float softplus_f(float x){ return fmaxf(x,0.0f) + log1pf(expf(-fabsf(x))); }

// ---------------- fused convert fp32 -> bf16 transposed; z<12: [1024][1024]; z==12: WpT [1088][1024] ----------------
__global__ __launch_bounds__(256) void k_cvtT13(const float* __restrict__ s0,
    const float* __restrict__ s1, const float* __restrict__ s2, const float* __restrict__ s3,
    const float* __restrict__ s4, __bf16* __restrict__ dst, __bf16* __restrict__ WpT){
  __shared__ float t[32][33];
  const size_t MM = (size_t)MDIM*MDIM;
  int z = blockIdx.z;
  int tx = threadIdx.x & 31, ty = threadIdx.x >> 5;
  if (z < 12){
    if (blockIdx.y >= 32) return;
    const float* s = (z<3)? s0 + (size_t)z*MM : (z<6)? s1 + (size_t)(z-3)*MM :
                     (z<9)? s2 + (size_t)(z-6)*MM : s3 + (size_t)(z-9)*MM;
    __bf16* d = dst + (size_t)z*MM;
    int k0 = blockIdx.y*32, n0 = blockIdx.x*32;
    #pragma unroll
    for (int r=0;r<32;r+=8) t[ty+r][tx] = s[(size_t)(k0+ty+r)*MDIM + n0+tx];
    __syncthreads();
    #pragma unroll
    for (int r=0;r<32;r+=8) d[(size_t)(n0+ty+r)*MDIM + k0+tx] = (__bf16)t[tx][ty+r];
  } else {
    int k0 = blockIdx.y*32, n0 = blockIdx.x*32;   // K=1088 (34 y-blocks), N=1024
    #pragma unroll
    for (int r=0;r<32;r+=8) t[ty+r][tx] = s4[(size_t)(k0+ty+r)*MDIM + n0+tx];
    __syncthreads();
    #pragma unroll
    for (int r=0;r<32;r+=8) WpT[(size_t)(n0+ty+r)*XLDB + k0+tx] = (__bf16)t[tx][ty+r];
  }
}

// ---------------- partial matvecs: P parts (solvent, y=0..4) + mol part (y=5) ----------------
__global__ __launch_bounds__(256) void k_pm(const float* __restrict__ sv,
    const float* __restrict__ spW, const float* __restrict__ mol,
    const float* __restrict__ bhw, float* __restrict__ PART){
  int s = blockIdx.y;
  int j = blockIdx.x*256 + threadIdx.x;
  int z = blockIdx.z, k0 = z*64;
  if (s < NSOL){
    const float* w = spW + (size_t)s*MDIM*MDIM + (size_t)k0*MDIM + j;
    const float* v = sv + s*MDIM + k0;
    float acc = 0.f;
    for (int k=0;k<64;k++) acc = fmaf(v[k], w[(size_t)k*MDIM], acc);
    PART[(size_t)z*NRED + s*MDIM + j] = acc;
  } else {
    const float* w = bhw + (size_t)k0*MDIM + j;
    float acc = 0.f;
    for (int k=0;k<64;k++) acc = fmaf(mol[k0+k], w[(size_t)k*MDIM], acc);
    PART[(size_t)z*NRED + 5120 + j] = acc;
  }
}

// ---------------- reduce partials -> P, mp(+bias); also init speculative state ----------------
__global__ __launch_bounds__(256) void k_red(const float* __restrict__ PART,
    const float* __restrict__ bhb, float* __restrict__ P, float* __restrict__ mp,
    float* __restrict__ prevg, int* __restrict__ dlist, int* __restrict__ dcnt){
  int i = blockIdx.x*256 + threadIdx.x;
  if (i < TSEQ){ prevg[i] = (i==0)? -1.0f : 1.0f; dlist[i] = i; }
  if (i == 0) *dcnt = TSEQ;
  float a = 0.f;
  #pragma unroll
  for (int z=0;z<16;z++) a += PART[(size_t)z*NRED + i];
  if (i < 5120) P[i] = a;
  else mp[i-5120] = a + bhb[i-5120];
}

// ---------------- fused sp0 + demb (bf16 only) ----------------
__global__ __launch_bounds__(256) void k_sp0d(const float* __restrict__ ratios,
    const float* __restrict__ P, const float* __restrict__ bias,
    const float* __restrict__ desc, const float* __restrict__ dw,
    const float* __restrict__ db, __bf16* __restrict__ Xb){
  int t = blockIdx.y;
  if (blockIdx.x < 4){
    int j = blockIdx.x*256 + threadIdx.x;
    const float* r = ratios + t*NSOL;
    float acc = bias[j];
    #pragma unroll
    for (int s=0;s<NSOL;s++) acc = fmaf(r[s], P[s*MDIM+j], acc);
    Xb[(size_t)t*XLDB + j] = (__bf16)gelu_f(acc);
  } else if (threadIdx.x < DED){
    int e = threadIdx.x;
    const float* d = desc + t*6;
    float acc = db[e];
    #pragma unroll
    for (int c=0;c<6;c++) acc = fmaf(d[c], dw[c*DED+e], acc);
    Xb[(size_t)t*XLDB + MDIM + e] = (__bf16)gelu_f(acc);
  }
}

// ---------------- bf16 MFMA GEMM, glds + chunk-swizzle + 2-phase dbuf, 512 thr ----------------
// BM=128, BN=64, template BK. 8 waves (4r x 2c), each 32x32 = 2x2 16x16 frags.
// Residual R is bf16.
template<int BK, bool GELU, bool RES, bool OUTF, bool OUTB, bool Z0>
__global__ __launch_bounds__(512) void k_mfma_gemm(
    const __bf16* __restrict__ A, int lda, int K,
    const __bf16* __restrict__ Bt,           // [N][K] bf16
    const float* __restrict__ bias,          // [N] fp32
    const __bf16* __restrict__ R, int ldr,   // bf16 residual
    float* __restrict__ Cf, int ldcf,
    __bf16* __restrict__ Cb, int ldcb,
    const float* __restrict__ wlast, const float* __restrict__ prevg,
    __bf16* __restrict__ Z0b)
{
  constexpr int CPR = BK/8;        // 16B chunks per row
  constexpr int AG  = BK/32;       // A stage groups per thread
  constexpr int BG  = (BK>=64)? BK/64 : 1;
  constexpr int KS  = BK/32;       // k-subtiles per tile
  __shared__ __attribute__((aligned(16))) __bf16 As[2][128*BK];
  __shared__ __attribute__((aligned(16))) __bf16 Bs[2][64*BK];
  int tid = threadIdx.x;
  int wave = tid>>6, lane = tid&63;
  int row0 = blockIdx.y*128, col0 = blockIdx.x*64;
  int wr = (wave>>1)*32, wc = (wave&1)*32;
  int lr = lane&15;
  f32x4 acc[2][2] = {};
  int NT = K / BK;

  auto stage = [&](int b, int k0){
    #pragma unroll
    for (int p=0;p<AG;p++){
      int q = wave*(AG*64) + p*64 + lane;      // A chunk id
      int r = q/CPR, c = q%CPR, cl = c^(r&7);
      GLDS16(A + (size_t)(row0+r)*lda + k0 + cl*8, &As[b][(wave*(AG*64)+p*64)*8]);
    }
    #pragma unroll
    for (int p=0;p<BG;p++){
      int q = wave*(BG*64) + p*64 + lane;      // B chunk id
      int r = q/CPR, c = q%CPR, cl = c^(r&7);
      GLDS16(Bt + (size_t)(col0+r)*K + k0 + cl*8, &Bs[b][(wave*(BG*64)+p*64)*8]);
    }
  };

  stage(0, 0);
  for (int t=0; t<NT; t++){
    __syncthreads();                           // drains stage(t) + protects buffer reuse
    if (t+1 < NT) stage((t+1)&1, (t+1)*BK);    // issue next tile's loads
    int b = t&1;
    #pragma unroll
    for (int ks=0;ks<KS;ks++){
      int c = ks*4 + (lane>>4);                // logical chunk = kk>>3
      bf16x8 af[2], bg[2];
      #pragma unroll
      for (int m=0;m<2;m++){
        int rowA = wr + m*16 + lr;
        af[m] = *(const bf16x8*)&As[b][rowA*BK + ((c ^ (rowA&7))<<3)];
      }
      #pragma unroll
      for (int n=0;n<2;n++){
        int rowB = wc + n*16 + lr;
        bg[n] = *(const bf16x8*)&Bs[b][rowB*BK + ((c ^ (rowB&7))<<3)];
      }
      #pragma unroll
      for (int m=0;m<2;m++)
        #pragma unroll
        for (int n=0;n<2;n++)
          acc[m][n] = __builtin_amdgcn_mfma_f32_16x16x32_bf16(af[m], bg[n], acc[m][n], 0,0,0);
    }
  }
  int rq = (lane>>4)*4;  // verified C/D layout: col = lane&15, row = (lane>>4)*4 + q
  #pragma unroll
  for (int m=0;m<2;m++){
    #pragma unroll
    for (int n=0;n<2;n++){
      int cc = col0 + wc + n*16 + lr;
      float bv = bias[cc];
      #pragma unroll
      for (int q=0;q<4;q++){
        int r = row0 + wr + m*16 + rq + q;
        float v = acc[m][n][q] + bv;
        if (RES)  v += (float)R[(size_t)r*ldr + cc];
        if (GELU) v = gelu_f(v);
        if (OUTF) Cf[(size_t)r*ldcf + cc] = v;
        if (OUTB) Cb[(size_t)r*ldcb + cc] = (__bf16)v;
        if (Z0)   Z0b[(size_t)r*MDIM + cc] = (__bf16)gelu_f(v + prevg[r]*wlast[cc]);
      }
    }
  }
}

// ---------------- batched LayerNorm (float4) -> bf16, optional fused mu/phi ----------------
template<bool MUPHI>
__global__ __launch_bounds__(256) void k_ln(const float* __restrict__ Y, int ldy,
    __bf16* __restrict__ Xb, int ldxb,
    const float* __restrict__ g, const float* __restrict__ b,
    const float* __restrict__ muw, const float* __restrict__ mub,
    const float* __restrict__ phiw, const float* __restrict__ phib,
    float* __restrict__ muA, float* __restrict__ phiA)
{
  int t = blockIdx.x;
  __shared__ float red[16];
  int tid = threadIdx.x;
  f32x4 y = *(const f32x4*)&Y[(size_t)t*ldy + tid*4];
  float s  = y[0]+y[1]+y[2]+y[3];
  float s2 = y[0]*y[0]+y[1]*y[1]+y[2]*y[2]+y[3]*y[3];
  for (int o=32;o>0;o>>=1){ s += __shfl_down(s,o); s2 += __shfl_down(s2,o); }
  int wid = tid>>6, lane = tid&63;
  if (lane==0){ red[wid]=s; red[wid+8]=s2; }
  __syncthreads();
  if (tid==0){
    float a=0.f,c=0.f;
    for (int w=0;w<4;w++){ a+=red[w]; c+=red[w+8]; }
    red[0]=a; red[8]=c;
  }
  __syncthreads();
  float mean = red[0]*(1.0f/MDIM);
  float var  = red[8]*(1.0f/MDIM) - mean*mean;
  float rs = rsqrtf(var + 1e-5f);
  f32x4 gv = *(const f32x4*)&g[tid*4];
  f32x4 bb = *(const f32x4*)&b[tid*4];
  f32x4 v; bf16x4 vb;
  #pragma unroll
  for (int i=0;i<4;i++){ v[i] = gv[i]*(y[i]-mean)*rs + bb[i]; vb[i] = (__bf16)v[i]; }
  *(bf16x4*)&Xb[(size_t)t*ldxb + tid*4] = vb;
  if (MUPHI){
    f32x4 mw = *(const f32x4*)&muw[tid*4];
    f32x4 pw = *(const f32x4*)&phiw[tid*4];
    float sm=0.f, sp=0.f;
    #pragma unroll
    for (int i=0;i<4;i++){ sm = fmaf(v[i], mw[i], sm); sp = fmaf(v[i], pw[i], sp); }
    for (int o=32;o>0;o>>=1){ sm+=__shfl_down(sm,o); sp+=__shfl_down(sp,o); }
    __syncthreads();
    if (lane==0){ red[wid]=sm; red[wid+8]=sp; }
    __syncthreads();
    if (tid==0){
      float a=0.f,c=0.f;
      for (int w=0;w<4;w++){ a+=red[w]; c+=red[w+8]; }
      muA[t]  = sigmoid_f(a + mub[0]);
      phiA[t] = softplus_f(c + phib[0]) + 2.0f;
    }
  }
}

// ================= dirty-row refinement stages (staged, 16-way j-split, 64 thr) =================

// fused z0 + fc1 (head block 0) for dirty rows
__global__ __launch_bounds__(64) void k_fc1z_dirty(
    const float* __restrict__ ZP, const float* __restrict__ wlast,
    const float* __restrict__ prevg,
    const __bf16* __restrict__ Wt, const float* __restrict__ bias,
    const int* __restrict__ dlist, const int* __restrict__ dcnt,
    __bf16* __restrict__ Zb, __bf16* __restrict__ Ob)
{
  __shared__ __bf16 zl[MDIM];
  int nd = *dcnt;
  int jb = blockIdx.x;
  int j = jb*64 + threadIdx.x;
  for (int rs = blockIdx.y; rs < nd; rs += RST){
    int t = dlist[rs];
    float prev = prevg[t];
    #pragma unroll
    for (int q=0;q<16;q++){
      int k = threadIdx.x + 64*q;
      __bf16 v = (__bf16)gelu_f(ZP[(size_t)t*MDIM + k] + prev*wlast[k]);
      zl[k] = v;
      if (jb==0) Zb[(size_t)t*MDIM + k] = v;
    }
    __syncthreads();
    const __bf16* w = Wt + (size_t)j*MDIM;
    float acc = 0.f;
    for (int k=0;k<MDIM;k+=8){
      bf16x8 wv = *(const bf16x8*)&w[k];
      bf16x8 iv = *(const bf16x8*)&zl[k];
      #pragma unroll
      for (int u=0;u<8;u++) acc = fmaf((float)wv[u], (float)iv[u], acc);
    }
    Ob[(size_t)t*MDIM + j] = (__bf16)gelu_f(acc + bias[j]);
    __syncthreads();
  }
}

// fc2 + bf16 residual -> Y fp32, dirty rows
__global__ __launch_bounds__(64) void k_fc2_dirty(
    const __bf16* __restrict__ In, const __bf16* __restrict__ Wt,
    const float* __restrict__ bias, const __bf16* __restrict__ Rz,
    const int* __restrict__ dlist, const int* __restrict__ dcnt,
    float* __restrict__ Of)
{
  int nd = *dcnt;
  int j = blockIdx.x*64 + threadIdx.x;
  for (int rs = blockIdx.y; rs < nd; rs += RST){
    int t = dlist[rs];
    const __bf16* in = In + (size_t)t*MDIM;
    const __bf16* w  = Wt + (size_t)j*MDIM;
    float acc = 0.f;
    for (int k=0;k<MDIM;k+=8){
      bf16x8 wv = *(const bf16x8*)&w[k];
      bf16x8 iv = *(const bf16x8*)&in[k];
      #pragma unroll
      for (int u=0;u<8;u++) acc = fmaf((float)wv[u], (float)iv[u], acc);
    }
    Of[(size_t)t*MDIM + j] = acc + bias[j] + (float)Rz[(size_t)t*MDIM + j];
  }
}

// fused LN (of Y) + fc1 matvec for dirty rows: single-wave LN -> LDS, then 64-output matvec
__global__ __launch_bounds__(64) void k_lnfc1_dirty(
    const float* __restrict__ Y,
    const float* __restrict__ g, const float* __restrict__ b,
    const __bf16* __restrict__ Wt, const float* __restrict__ fbias,
    const int* __restrict__ dlist, const int* __restrict__ dcnt,
    __bf16* __restrict__ Zb, __bf16* __restrict__ Ob)
{
  __shared__ __bf16 zl[MDIM];
  int nd = *dcnt;
  int jb = blockIdx.x;
  int j = jb*64 + threadIdx.x;
  for (int rs = blockIdx.y; rs < nd; rs += RST){
    int t = dlist[rs];
    float y[16]; float s=0.f, s2=0.f;
    #pragma unroll
    for (int q=0;q<16;q++){
      y[q] = Y[(size_t)t*MDIM + threadIdx.x + 64*q];
      s += y[q]; s2 += y[q]*y[q];
    }
    for (int o=32;o>0;o>>=1){ s += __shfl_down(s,o); s2 += __shfl_down(s2,o); }
    float tot  = __shfl(s, 0);
    float tot2 = __shfl(s2, 0);
    float mean = tot*(1.0f/MDIM);
    float var  = tot2*(1.0f/MDIM) - mean*mean;
    float rs2 = rsqrtf(var + 1e-5f);
    #pragma unroll
    for (int q=0;q<16;q++){
      int k = threadIdx.x + 64*q;
      __bf16 v = (__bf16)(g[k]*(y[q]-mean)*rs2 + b[k]);
      zl[k] = v;
      if (jb==0) Zb[(size_t)t*MDIM + k] = v;
    }
    __syncthreads();
    const __bf16* w = Wt + (size_t)j*MDIM;
    float acc = 0.f;
    for (int k=0;k<MDIM;k+=8){
      bf16x8 wv = *(const bf16x8*)&w[k];
      bf16x8 iv = *(const bf16x8*)&zl[k];
      #pragma unroll
      for (int u=0;u<8;u++) acc = fmaf((float)wv[u], (float)iv[u], acc);
    }
    Ob[(size_t)t*MDIM + j] = (__bf16)gelu_f(acc + fbias[j]);
    __syncthreads();
  }
}

// final LN + mu/phi for dirty rows (single wave per row-slot, 64 thr)
__global__ __launch_bounds__(64) void k_lnmp_dirty(
    const float* __restrict__ Y,
    const float* __restrict__ g, const float* __restrict__ b,
    const int* __restrict__ dlist, const int* __restrict__ dcnt,
    const float* __restrict__ muw, const float* __restrict__ mub,
    const float* __restrict__ phiw, const float* __restrict__ phib,
    float* __restrict__ muA, float* __restrict__ phiA)
{
  int nd = *dcnt;
  for (int rs = blockIdx.x; rs < nd; rs += RST){
    int t = dlist[rs];
    float y[16]; float s=0.f, s2=0.f;
    #pragma unroll
    for (int q=0;q<16;q++){
      y[q] = Y[(size_t)t*MDIM + threadIdx.x + 64*q];
      s += y[q]; s2 += y[q]*y[q];
    }
    for (int o=32;o>0;o>>=1){ s += __shfl_down(s,o); s2 += __shfl_down(s2,o); }
    float tot  = __shfl(s, 0);
    float tot2 = __shfl(s2, 0);
    float mean = tot*(1.0f/MDIM);
    float var  = tot2*(1.0f/MDIM) - mean*mean;
    float rs2 = rsqrtf(var + 1e-5f);
    float sm=0.f, sp=0.f;
    #pragma unroll
    for (int q=0;q<16;q++){
      int k = threadIdx.x + 64*q;
      float v = g[k]*(y[q]-mean)*rs2 + b[k];
      sm = fmaf(v, muw[k], sm); sp = fmaf(v, phiw[k], sp);
    }
    for (int o=32;o>0;o>>=1){ sm+=__shfl_down(sm,o); sp+=__shfl_down(sp,o); }
    if (threadIdx.x==0){
      muA[t]  = sigmoid_f(sm + mub[0]);
      phiA[t] = softplus_f(sp + phib[0]) + 2.0f;
    }
  }
}

// ---------------- segmented prefix-product scan + dirty detection + output ----------------
__global__ __launch_bounds__(1024) void k_scan(
    const float* __restrict__ muA, const float* __restrict__ phiA,
    const unsigned char* __restrict__ bmask,
    float* __restrict__ prevg, int* __restrict__ dlist, int* __restrict__ dcnt,
    float* __restrict__ out)
{
  if (*dcnt == 0) return;   // converged: nothing changed since last scan
  __shared__ float v[2][TSEQ];
  __shared__ unsigned char f[2][TSEQ];
  __shared__ int cnt;
  int tid = threadIdx.x;
  if (tid==0) cnt = 0;
  for (int i=tid;i<TSEQ;i+=1024){
    v[0][i] = 1.0f - muA[i];
    f[0][i] = (i==0) || (bmask[i] != 0);
  }
  __syncthreads();
  int src=0;
  for (int off=1; off<TSEQ; off<<=1){
    int dst = src^1;
    for (int i=tid;i<TSEQ;i+=1024){
      float vv = v[src][i]; unsigned char ff = f[src][i];
      if (i>=off && !ff){ vv *= v[src][i-off]; ff = f[src][i-off]; }
      v[dst][i]=vv; f[dst][i]=ff;
    }
    __syncthreads();
    src = dst;
  }
  for (int i=tid;i<TSEQ;i+=1024){
    float rf = 1.0f - v[src][i];
    float prev = (i==0) ? -1.0f : (1.0f - v[src][i-1]);
    out[i]        = rf;
    out[TSEQ+i]   = muA[i];
    out[2*TSEQ+i] = phiA[i];
    float old = prevg[i];
    prevg[i] = prev;
    if (fabsf(prev - old) > 1e-3f){
      int pos = atomicAdd(&cnt, 1);
      dlist[pos] = i;
    }
  }
  __syncthreads();
  if (tid==0) *dcnt = cnt;
}

extern "C" void kernel_launch(void* const* d_in, const int* in_sizes, int n_in,
                              void* d_out, int out_size, void* d_ws, size_t ws_size,
                              hipStream_t stream) {
  const float* mol       = (const float*)d_in[0];
  const float* ratios    = (const float*)d_in[1];
  const float* desc      = (const float*)d_in[2];
  const float* svvec     = (const float*)d_in[3];
  const unsigned char* bmask = (const unsigned char*)d_in[4];
  const float* sp_proj_w = (const float*)d_in[5];
  const float* sp_proj_b = (const float*)d_in[6];
  const float* sp_fc1_w  = (const float*)d_in[7];
  const float* sp_fc1_b  = (const float*)d_in[8];
  const float* sp_fc2_w  = (const float*)d_in[9];
  const float* sp_fc2_b  = (const float*)d_in[10];
  const float* sp_ln_g   = (const float*)d_in[11];
  const float* sp_ln_b   = (const float*)d_in[12];
  const float* desc_w    = (const float*)d_in[13];
  const float* desc_b    = (const float*)d_in[14];
  const float* bh_proj_w = (const float*)d_in[15];
  const float* bh_proj_b = (const float*)d_in[16];
  const float* bh_fc1_w  = (const float*)d_in[17];
  const float* bh_fc1_b  = (const float*)d_in[18];
  const float* bh_fc2_w  = (const float*)d_in[19];
  const float* bh_fc2_b  = (const float*)d_in[20];
  const float* bh_ln_g   = (const float*)d_in[21];
  const float* bh_ln_b   = (const float*)d_in[22];
  const float* mu_w      = (const float*)d_in[23];
  const float* mu_b      = (const float*)d_in[24];
  const float* phi_w     = (const float*)d_in[25];
  const float* phi_b     = (const float*)d_in[26];
  float* out = (float*)d_out;

  char* p = (char*)d_ws;
  auto alloc = [&](size_t bytes)->char*{ char* r = p; p += (bytes + 255) & ~(size_t)255; return r; };
  const size_t MM = (size_t)MDIM*MDIM;
  __bf16* Xb   = (__bf16*)alloc((size_t)TSEQ*XLDB*2);    // bf16 [sp|demb]
  __bf16* Zb   = (__bf16*)alloc((size_t)TSEQ*MDIM*2);    // head bf16 z
  float*  Y    = (float*)alloc((size_t)TSEQ*MDIM*4);     // fp32 pre-LN
  float*  ZP   = (float*)alloc((size_t)TSEQ*MDIM*4);     // persistent head pre-activation
  __bf16* Hb16 = (__bf16*)alloc((size_t)TSEQ*MDIM*2);
  __bf16* WALL = (__bf16*)alloc(12*MM*2);                // W1T|W2T|U1T|U2T (3 blocks each)
  __bf16* WpT  = (__bf16*)alloc((size_t)MDIM*XLDB*2);    // [1024][1088]
  float*  PART = (float*)alloc((size_t)16*NRED*4);
  float*  P    = (float*)alloc((size_t)NSOL*MDIM*4);
  float*  mp   = (float*)alloc(MDIM*4);
  float*  prevg= (float*)alloc(TSEQ*4);
  float*  muA  = (float*)alloc(TSEQ*4);
  float*  phiA = (float*)alloc(TSEQ*4);
  int*    dlist= (int*)alloc(TSEQ*4);
  int*    dcnt = (int*)alloc(256);
  __bf16* W1T = WALL, *W2T = WALL + 3*MM, *U1T = WALL + 6*MM, *U2T = WALL + 9*MM;

  k_cvtT13<<<dim3(32,34,13),256,0,stream>>>(sp_fc1_w, sp_fc2_w, bh_fc1_w, bh_fc2_w,
      bh_proj_w + MM, WALL, WpT);
  k_pm<<<dim3(4,6,16),256,0,stream>>>(svvec, sp_proj_w, mol, bh_proj_w, PART);
  k_red<<<dim3(NRED/256),256,0,stream>>>(PART, bh_proj_b, P, mp, prevg, dlist, dcnt);
  k_sp0d<<<dim3(5,TSEQ),256,0,stream>>>(ratios, P, sp_proj_b, desc, desc_w, desc_b, Xb);

  const float* wlast = bh_proj_w + (size_t)2112*MDIM;
  // sp residual chain (bf16 MFMA GEMMs, BK=128)
  for (int i=0;i<NBLK;i++){
    k_mfma_gemm<128,true,false,false,true,false><<<dim3(16,16),512,0,stream>>>(
        Xb, XLDB, MDIM, W1T + i*MM, sp_fc1_b + i*MDIM, nullptr, 0,
        nullptr, 0, Hb16, MDIM, nullptr, nullptr, nullptr);
    k_mfma_gemm<128,false,true,true,false,false><<<dim3(16,16),512,0,stream>>>(
        Hb16, MDIM, MDIM, W2T + i*MM, sp_fc2_b + i*MDIM, Xb, XLDB,
        Y, MDIM, nullptr, 0, nullptr, nullptr, nullptr);
    k_ln<false><<<dim3(TSEQ),256,0,stream>>>(Y, MDIM, Xb, XLDB,
        sp_ln_g + i*MDIM, sp_ln_b + i*MDIM,
        nullptr, nullptr, nullptr, nullptr, nullptr, nullptr);
  }
  // z_pre GEMM (K=1088, BK=64) with fused z0 epilogue: ZP + speculative gelu -> Zb
  k_mfma_gemm<64,false,false,true,false,true><<<dim3(16,16),512,0,stream>>>(
      Xb, XLDB, XLDB, WpT, mp, nullptr, 0, ZP, MDIM, nullptr, 0,
      wlast, prevg, Zb);

  // ---- iteration 1: batched head with speculative prev ----
  for (int i=0;i<NBLK;i++){
    k_mfma_gemm<128,true,false,false,true,false><<<dim3(16,16),512,0,stream>>>(
        Zb, MDIM, MDIM, U1T + i*MM, bh_fc1_b + i*MDIM, nullptr, 0,
        nullptr, 0, Hb16, MDIM, nullptr, nullptr, nullptr);
    k_mfma_gemm<128,false,true,true,false,false><<<dim3(16,16),512,0,stream>>>(
        Hb16, MDIM, MDIM, U2T + i*MM, bh_fc2_b + i*MDIM, Zb, MDIM,
        Y, MDIM, nullptr, 0, nullptr, nullptr, nullptr);
    if (i < NBLK-1)
      k_ln<false><<<dim3(TSEQ),256,0,stream>>>(Y, MDIM, Zb, MDIM,
          bh_ln_g + i*MDIM, bh_ln_b + i*MDIM,
          nullptr, nullptr, nullptr, nullptr, nullptr, nullptr);
    else
      k_ln<true><<<dim3(TSEQ),256,0,stream>>>(Y, MDIM, Zb, MDIM,
          bh_ln_g + i*MDIM, bh_ln_b + i*MDIM,
          mu_w, mu_b, phi_w, phi_b, muA, phiA);
  }
  k_scan<<<dim3(1),1024,0,stream>>>(muA, phiA, bmask, prevg, dlist, dcnt, out);

  // ---- refinement iterations: staged dirty-row head (16-way j-split, 64 thr) ----
  for (int it=1; it<KITER; it++){
    k_fc1z_dirty<<<dim3(16,RST),64,0,stream>>>(ZP, wlast, prevg,
        U1T, bh_fc1_b, dlist, dcnt, Zb, Hb16);
    k_fc2_dirty<<<dim3(16,RST),64,0,stream>>>(
        Hb16, U2T, bh_fc2_b, Zb, dlist, dcnt, Y);
    for (int i=1;i<NBLK;i++){
      k_lnfc1_dirty<<<dim3(16,RST),64,0,stream>>>(Y,
          bh_ln_g + (i-1)*MDIM, bh_ln_b + (i-1)*MDIM,
          U1T + i*MM, bh_fc1_b + i*MDIM, dlist, dcnt, Zb, Hb16);
      k_fc2_dirty<<<dim3(16,RST),64,0,stream>>>(
          Hb16, U2T + i*MM, bh_fc2_b + i*MDIM, Zb, dlist, dcnt, Y);
    }
    k_lnmp_dirty<<<dim3(RST),64,0,stream>>>(Y,
        bh_ln_g + (NBLK-1)*MDIM, bh_ln_b + (NBLK-1)*MDIM,
        dlist, dcnt, mu_w, mu_b, phi_w, phi_b, muA, phiA);
    k_scan<<<dim3(1),1024,0,stream>>>(muA, phiA, bmask, prevg, dlist, dcnt, out);
  }
  (void)in_sizes; (void)n_in; (void)out_size; (void)ws_size;
}

// Round 9
// 365.906 us; speedup vs baseline: 3.1651x; 1.0505x over previous
//
#include <hip/hip_runtime.h>
#include <math.h>

#define MDIM 1024
#define TSEQ 2048
#define NSOL 5
#define DED  64
#define NBLK 3
#define KITER 2
#define XLDB 1088   // bf16 X leading dim: 1024 sp cols + 64 demb cols
#define NRED 6144   // 5120 P cols + 1024 mp cols
#define RST  64     // dirty-stage grid row stride

typedef __bf16 bf16x8 __attribute__((ext_vector_type(8)));
typedef __bf16 bf16x4 __attribute__((ext_vector_type(4)));
typedef float  f32x4  __attribute__((ext_vector_type(4)));

#define GLDS16(gptr, lptr) __builtin_amdgcn_global_load_lds( \
    (const __attribute__((address_space(1))) unsigned int*)(const void*)(gptr), \
    (__attribute__((address_space(3))) unsigned int*)(void*)(lptr), 16, 0, 0)

__device__ __forceinline__ float gelu_f(float x){
  return 0.5f * x * (1.0f + erff(x * 0.70710678118654752440f));
}
__device__ __forceinline__ float sigmoid_f(float x){ return 1.0f/(1.0f+expf(-x)); }
__device__ __forceinline__ float softplus_f(float x){ return fmaxf(x,0.0f) + log1pf(expf(-fabsf(x))); }

// ---------------- fused convert fp32 -> bf16 transposed; z<12: [1024][1024]; z==12: WpT [1088][1024] ----------------
__global__ __launch_bounds__(256) void k_cvtT13(const float* __restrict__ s0,
    const float* __restrict__ s1, const float* __restrict__ s2, const float* __restrict__ s3,
    const float* __restrict__ s4, __bf16* __restrict__ dst, __bf16* __restrict__ WpT){
  __shared__ float t[32][33];
  const size_t MM = (size_t)MDIM*MDIM;
  int z = blockIdx.z;
  int tx = threadIdx.x & 31, ty = threadIdx.x >> 5;
  if (z < 12){
    if (blockIdx.y >= 32) return;
    const float* s = (z<3)? s0 + (size_t)z*MM : (z<6)? s1 + (size_t)(z-3)*MM :
                     (z<9)? s2 + (size_t)(z-6)*MM : s3 + (size_t)(z-9)*MM;
    __bf16* d = dst + (size_t)z*MM;
    int k0 = blockIdx.y*32, n0 = blockIdx.x*32;
    #pragma unroll
    for (int r=0;r<32;r+=8) t[ty+r][tx] = s[(size_t)(k0+ty+r)*MDIM + n0+tx];
    __syncthreads();
    #pragma unroll
    for (int r=0;r<32;r+=8) d[(size_t)(n0+ty+r)*MDIM + k0+tx] = (__bf16)t[tx][ty+r];
  } else {
    int k0 = blockIdx.y*32, n0 = blockIdx.x*32;   // K=1088 (34 y-blocks), N=1024
    #pragma unroll
    for (int r=0;r<32;r+=8) t[ty+r][tx] = s4[(size_t)(k0+ty+r)*MDIM + n0+tx];
    __syncthreads();
    #pragma unroll
    for (int r=0;r<32;r+=8) WpT[(size_t)(n0+ty+r)*XLDB + k0+tx] = (__bf16)t[tx][ty+r];
  }
}

// ---------------- partial matvecs: P parts (solvent, y=0..4) + mol part (y=5) ----------------
__global__ __launch_bounds__(256) void k_pm(const float* __restrict__ sv,
    const float* __restrict__ spW, const float* __restrict__ mol,
    const float* __restrict__ bhw, float* __restrict__ PART){
  int s = blockIdx.y;
  int j = blockIdx.x*256 + threadIdx.x;
  int z = blockIdx.z, k0 = z*64;
  if (s < NSOL){
    const float* w = spW + (size_t)s*MDIM*MDIM + (size_t)k0*MDIM + j;
    const float* v = sv + s*MDIM + k0;
    float acc = 0.f;
    for (int k=0;k<64;k++) acc = fmaf(v[k], w[(size_t)k*MDIM], acc);
    PART[(size_t)z*NRED + s*MDIM + j] = acc;
  } else {
    const float* w = bhw + (size_t)k0*MDIM + j;
    float acc = 0.f;
    for (int k=0;k<64;k++) acc = fmaf(mol[k0+k], w[(size_t)k*MDIM], acc);
    PART[(size_t)z*NRED + 5120 + j] = acc;
  }
}

// ---------------- reduce partials -> P, mp(+bias); also init speculative state ----------------
__global__ __launch_bounds__(256) void k_red(const float* __restrict__ PART,
    const float* __restrict__ bhb, float* __restrict__ P, float* __restrict__ mp,
    float* __restrict__ prevg, int* __restrict__ dlist, int* __restrict__ dcnt){
  int i = blockIdx.x*256 + threadIdx.x;
  if (i < TSEQ){ prevg[i] = (i==0)? -1.0f : 1.0f; dlist[i] = i; }
  if (i == 0) *dcnt = TSEQ;
  float a = 0.f;
  #pragma unroll
  for (int z=0;z<16;z++) a += PART[(size_t)z*NRED + i];
  if (i < 5120) P[i] = a;
  else mp[i-5120] = a + bhb[i-5120];
}

// ---------------- fused sp0 + demb (bf16 only) ----------------
__global__ __launch_bounds__(256) void k_sp0d(const float* __restrict__ ratios,
    const float* __restrict__ P, const float* __restrict__ bias,
    const float* __restrict__ desc, const float* __restrict__ dw,
    const float* __restrict__ db, __bf16* __restrict__ Xb){
  int t = blockIdx.y;
  if (blockIdx.x < 4){
    int j = blockIdx.x*256 + threadIdx.x;
    const float* r = ratios + t*NSOL;
    float acc = bias[j];
    #pragma unroll
    for (int s=0;s<NSOL;s++) acc = fmaf(r[s], P[s*MDIM+j], acc);
    Xb[(size_t)t*XLDB + j] = (__bf16)gelu_f(acc);
  } else if (threadIdx.x < DED){
    int e = threadIdx.x;
    const float* d = desc + t*6;
    float acc = db[e];
    #pragma unroll
    for (int c=0;c<6;c++) acc = fmaf(d[c], dw[c*DED+e], acc);
    Xb[(size_t)t*XLDB + MDIM + e] = (__bf16)gelu_f(acc);
  }
}

// ---------------- bf16 MFMA GEMM, glds + chunk-swizzle + 2-phase dbuf, 512 thr ----------------
// BM=128, BN=64, template BK. 8 waves (4r x 2c), each 32x32 = 2x2 16x16 frags.
// Residual R is bf16.
template<int BK, bool GELU, bool RES, bool OUTF, bool OUTB, bool Z0>
__global__ __launch_bounds__(512) void k_mfma_gemm(
    const __bf16* __restrict__ A, int lda, int K,
    const __bf16* __restrict__ Bt,           // [N][K] bf16
    const float* __restrict__ bias,          // [N] fp32
    const __bf16* __restrict__ R, int ldr,   // bf16 residual
    float* __restrict__ Cf, int ldcf,
    __bf16* __restrict__ Cb, int ldcb,
    const float* __restrict__ wlast, const float* __restrict__ prevg,
    __bf16* __restrict__ Z0b)
{
  constexpr int CPR = BK/8;        // 16B chunks per row
  constexpr int AG  = BK/32;       // A stage groups per thread
  constexpr int BG  = (BK>=64)? BK/64 : 1;
  constexpr int KS  = BK/32;       // k-subtiles per tile
  __shared__ __attribute__((aligned(16))) __bf16 As[2][128*BK];
  __shared__ __attribute__((aligned(16))) __bf16 Bs[2][64*BK];
  int tid = threadIdx.x;
  int wave = tid>>6, lane = tid&63;
  int row0 = blockIdx.y*128, col0 = blockIdx.x*64;
  int wr = (wave>>1)*32, wc = (wave&1)*32;
  int lr = lane&15;
  f32x4 acc[2][2] = {};
  int NT = K / BK;

  auto stage = [&](int b, int k0){
    #pragma unroll
    for (int p=0;p<AG;p++){
      int q = wave*(AG*64) + p*64 + lane;      // A chunk id
      int r = q/CPR, c = q%CPR, cl = c^(r&7);
      GLDS16(A + (size_t)(row0+r)*lda + k0 + cl*8, &As[b][(wave*(AG*64)+p*64)*8]);
    }
    #pragma unroll
    for (int p=0;p<BG;p++){
      int q = wave*(BG*64) + p*64 + lane;      // B chunk id
      int r = q/CPR, c = q%CPR, cl = c^(r&7);
      GLDS16(Bt + (size_t)(col0+r)*K + k0 + cl*8, &Bs[b][(wave*(BG*64)+p*64)*8]);
    }
  };

  stage(0, 0);
  for (int t=0; t<NT; t++){
    __syncthreads();                           // drains stage(t) + protects buffer reuse
    if (t+1 < NT) stage((t+1)&1, (t+1)*BK);    // issue next tile's loads
    int b = t&1;
    #pragma unroll
    for (int ks=0;ks<KS;ks++){
      int c = ks*4 + (lane>>4);                // logical chunk = kk>>3
      bf16x8 af[2], bg[2];
      #pragma unroll
      for (int m=0;m<2;m++){
        int rowA = wr + m*16 + lr;
        af[m] = *(const bf16x8*)&As[b][rowA*BK + ((c ^ (rowA&7))<<3)];
      }
      #pragma unroll
      for (int n=0;n<2;n++){
        int rowB = wc + n*16 + lr;
        bg[n] = *(const bf16x8*)&Bs[b][rowB*BK + ((c ^ (rowB&7))<<3)];
      }
      #pragma unroll
      for (int m=0;m<2;m++)
        #pragma unroll
        for (int n=0;n<2;n++)
          acc[m][n] = __builtin_amdgcn_mfma_f32_16x16x32_bf16(af[m], bg[n], acc[m][n], 0,0,0);
    }
  }
  int rq = (lane>>4)*4;  // verified C/D layout: col = lane&15, row = (lane>>4)*4 + q
  #pragma unroll
  for (int m=0;m<2;m++){
    #pragma unroll
    for (int n=0;n<2;n++){
      int cc = col0 + wc + n*16 + lr;
      float bv = bias[cc];
      #pragma unroll
      for (int q=0;q<4;q++){
        int r = row0 + wr + m*16 + rq + q;
        float v = acc[m][n][q] + bv;
        if (RES)  v += (float)R[(size_t)r*ldr + cc];
        if (GELU) v = gelu_f(v);
        if (OUTF) Cf[(size_t)r*ldcf + cc] = v;
        if (OUTB) Cb[(size_t)r*ldcb + cc] = (__bf16)v;
        if (Z0)   Z0b[(size_t)r*MDIM + cc] = (__bf16)gelu_f(v + prevg[r]*wlast[cc]);
      }
    }
  }
}

// ---------------- batched LayerNorm (float4) -> bf16, optional fused mu/phi ----------------
template<bool MUPHI>
__global__ __launch_bounds__(256) void k_ln(const float* __restrict__ Y, int ldy,
    __bf16* __restrict__ Xb, int ldxb,
    const float* __restrict__ g, const float* __restrict__ b,
    const float* __restrict__ muw, const float* __restrict__ mub,
    const float* __restrict__ phiw, const float* __restrict__ phib,
    float* __restrict__ muA, float* __restrict__ phiA)
{
  int t = blockIdx.x;
  __shared__ float red[16];
  int tid = threadIdx.x;
  f32x4 y = *(const f32x4*)&Y[(size_t)t*ldy + tid*4];
  float s  = y[0]+y[1]+y[2]+y[3];
  float s2 = y[0]*y[0]+y[1]*y[1]+y[2]*y[2]+y[3]*y[3];
  for (int o=32;o>0;o>>=1){ s += __shfl_down(s,o); s2 += __shfl_down(s2,o); }
  int wid = tid>>6, lane = tid&63;
  if (lane==0){ red[wid]=s; red[wid+8]=s2; }
  __syncthreads();
  if (tid==0){
    float a=0.f,c=0.f;
    for (int w=0;w<4;w++){ a+=red[w]; c+=red[w+8]; }
    red[0]=a; red[8]=c;
  }
  __syncthreads();
  float mean = red[0]*(1.0f/MDIM);
  float var  = red[8]*(1.0f/MDIM) - mean*mean;
  float rs = rsqrtf(var + 1e-5f);
  f32x4 gv = *(const f32x4*)&g[tid*4];
  f32x4 bb = *(const f32x4*)&b[tid*4];
  f32x4 v; bf16x4 vb;
  #pragma unroll
  for (int i=0;i<4;i++){ v[i] = gv[i]*(y[i]-mean)*rs + bb[i]; vb[i] = (__bf16)v[i]; }
  *(bf16x4*)&Xb[(size_t)t*ldxb + tid*4] = vb;
  if (MUPHI){
    f32x4 mw = *(const f32x4*)&muw[tid*4];
    f32x4 pw = *(const f32x4*)&phiw[tid*4];
    float sm=0.f, sp=0.f;
    #pragma unroll
    for (int i=0;i<4;i++){ sm = fmaf(v[i], mw[i], sm); sp = fmaf(v[i], pw[i], sp); }
    for (int o=32;o>0;o>>=1){ sm+=__shfl_down(sm,o); sp+=__shfl_down(sp,o); }
    __syncthreads();
    if (lane==0){ red[wid]=sm; red[wid+8]=sp; }
    __syncthreads();
    if (tid==0){
      float a=0.f,c=0.f;
      for (int w=0;w<4;w++){ a+=red[w]; c+=red[w+8]; }
      muA[t]  = sigmoid_f(a + mub[0]);
      phiA[t] = softplus_f(c + phib[0]) + 2.0f;
    }
  }
}

// ================= dirty-row refinement stages (staged, 16-way j-split, 64 thr) =================

// fused z0 + fc1 (head block 0) for dirty rows
__global__ __launch_bounds__(64) void k_fc1z_dirty(
    const float* __restrict__ ZP, const float* __restrict__ wlast,
    const float* __restrict__ prevg,
    const __bf16* __restrict__ Wt, const float* __restrict__ bias,
    const int* __restrict__ dlist, const int* __restrict__ dcnt,
    __bf16* __restrict__ Zb, __bf16* __restrict__ Ob)
{
  __shared__ __bf16 zl[MDIM];
  int nd = *dcnt;
  int jb = blockIdx.x;
  int j = jb*64 + threadIdx.x;
  for (int rs = blockIdx.y; rs < nd; rs += RST){
    int t = dlist[rs];
    float prev = prevg[t];
    #pragma unroll
    for (int q=0;q<16;q++){
      int k = threadIdx.x + 64*q;
      __bf16 v = (__bf16)gelu_f(ZP[(size_t)t*MDIM + k] + prev*wlast[k]);
      zl[k] = v;
      if (jb==0) Zb[(size_t)t*MDIM + k] = v;
    }
    __syncthreads();
    const __bf16* w = Wt + (size_t)j*MDIM;
    float acc = 0.f;
    for (int k=0;k<MDIM;k+=8){
      bf16x8 wv = *(const bf16x8*)&w[k];
      bf16x8 iv = *(const bf16x8*)&zl[k];
      #pragma unroll
      for (int u=0;u<8;u++) acc = fmaf((float)wv[u], (float)iv[u], acc);
    }
    Ob[(size_t)t*MDIM + j] = (__bf16)gelu_f(acc + bias[j]);
    __syncthreads();
  }
}

// fc2 + bf16 residual -> Y fp32, dirty rows
__global__ __launch_bounds__(64) void k_fc2_dirty(
    const __bf16* __restrict__ In, const __bf16* __restrict__ Wt,
    const float* __restrict__ bias, const __bf16* __restrict__ Rz,
    const int* __restrict__ dlist, const int* __restrict__ dcnt,
    float* __restrict__ Of)
{
  int nd = *dcnt;
  int j = blockIdx.x*64 + threadIdx.x;
  for (int rs = blockIdx.y; rs < nd; rs += RST){
    int t = dlist[rs];
    const __bf16* in = In + (size_t)t*MDIM;
    const __bf16* w  = Wt + (size_t)j*MDIM;
    float acc = 0.f;
    for (int k=0;k<MDIM;k+=8){
      bf16x8 wv = *(const bf16x8*)&w[k];
      bf16x8 iv = *(const bf16x8*)&in[k];
      #pragma unroll
      for (int u=0;u<8;u++) acc = fmaf((float)wv[u], (float)iv[u], acc);
    }
    Of[(size_t)t*MDIM + j] = acc + bias[j] + (float)Rz[(size_t)t*MDIM + j];
  }
}

// fused LN (of Y) + fc1 matvec for dirty rows: single-wave LN -> LDS, then 64-output matvec
__global__ __launch_bounds__(64) void k_lnfc1_dirty(
    const float* __restrict__ Y,
    const float* __restrict__ g, const float* __restrict__ b,
    const __bf16* __restrict__ Wt, const float* __restrict__ fbias,
    const int* __restrict__ dlist, const int* __restrict__ dcnt,
    __bf16* __restrict__ Zb, __bf16* __restrict__ Ob)
{
  __shared__ __bf16 zl[MDIM];
  int nd = *dcnt;
  int jb = blockIdx.x;
  int j = jb*64 + threadIdx.x;
  for (int rs = blockIdx.y; rs < nd; rs += RST){
    int t = dlist[rs];
    float y[16]; float s=0.f, s2=0.f;
    #pragma unroll
    for (int q=0;q<16;q++){
      y[q] = Y[(size_t)t*MDIM + threadIdx.x + 64*q];
      s += y[q]; s2 += y[q]*y[q];
    }
    for (int o=32;o>0;o>>=1){ s += __shfl_down(s,o); s2 += __shfl_down(s2,o); }
    float tot  = __shfl(s, 0);
    float tot2 = __shfl(s2, 0);
    float mean = tot*(1.0f/MDIM);
    float var  = tot2*(1.0f/MDIM) - mean*mean;
    float rs2 = rsqrtf(var + 1e-5f);
    #pragma unroll
    for (int q=0;q<16;q++){
      int k = threadIdx.x + 64*q;
      __bf16 v = (__bf16)(g[k]*(y[q]-mean)*rs2 + b[k]);
      zl[k] = v;
      if (jb==0) Zb[(size_t)t*MDIM + k] = v;
    }
    __syncthreads();
    const __bf16* w = Wt + (size_t)j*MDIM;
    float acc = 0.f;
    for (int k=0;k<MDIM;k+=8){
      bf16x8 wv = *(const bf16x8*)&w[k];
      bf16x8 iv = *(const bf16x8*)&zl[k];
      #pragma unroll
      for (int u=0;u<8;u++) acc = fmaf((float)wv[u], (float)iv[u], acc);
    }
    Ob[(size_t)t*MDIM + j] = (__bf16)gelu_f(acc + fbias[j]);
    __syncthreads();
  }
}

// final LN + mu/phi for dirty rows (single wave per row-slot, 64 thr)
__global__ __launch_bounds__(64) void k_lnmp_dirty(
    const float* __restrict__ Y,
    const float* __restrict__ g, const float* __restrict__ b,
    const int* __restrict__ dlist, const int* __restrict__ dcnt,
    const float* __restrict__ muw, const float* __restrict__ mub,
    const float* __restrict__ phiw, const float* __restrict__ phib,
    float* __restrict__ muA, float* __restrict__ phiA)
{
  int nd = *dcnt;
  for (int rs = blockIdx.x; rs < nd; rs += RST){
    int t = dlist[rs];
    float y[16]; float s=0.f, s2=0.f;
    #pragma unroll
    for (int q=0;q<16;q++){
      y[q] = Y[(size_t)t*MDIM + threadIdx.x + 64*q];
      s += y[q]; s2 += y[q]*y[q];
    }
    for (int o=32;o>0;o>>=1){ s += __shfl_down(s,o); s2 += __shfl_down(s2,o); }
    float tot  = __shfl(s, 0);
    float tot2 = __shfl(s2, 0);
    float mean = tot*(1.0f/MDIM);
    float var  = tot2*(1.0f/MDIM) - mean*mean;
    float rs2 = rsqrtf(var + 1e-5f);
    float sm=0.f, sp=0.f;
    #pragma unroll
    for (int q=0;q<16;q++){
      int k = threadIdx.x + 64*q;
      float v = g[k]*(y[q]-mean)*rs2 + b[k];
      sm = fmaf(v, muw[k], sm); sp = fmaf(v, phiw[k], sp);
    }
    for (int o=32;o>0;o>>=1){ sm+=__shfl_down(sm,o); sp+=__shfl_down(sp,o); }
    if (threadIdx.x==0){
      muA[t]  = sigmoid_f(sm + mub[0]);
      phiA[t] = softplus_f(sp + phib[0]) + 2.0f;
    }
  }
}

// ---------------- segmented prefix-product scan (wave shfl, 2 barriers) + dirty detect + output ----------------
__global__ __launch_bounds__(1024) void k_scan(
    const float* __restrict__ muA, const float* __restrict__ phiA,
    const unsigned char* __restrict__ bmask,
    float* __restrict__ prevg, int* __restrict__ dlist, int* __restrict__ dcnt,
    float* __restrict__ out)
{
  if (*dcnt == 0) return;
  __shared__ float aggP[16];
  __shared__ unsigned aggF[16];
  __shared__ float wprP[16];
  __shared__ unsigned wprF[16];
  __shared__ int cnt;
  int tid = threadIdx.x;
  int wid = tid>>6, lane = tid&63;
  if (tid==0) cnt = 0;
  int i0 = wid*128 + lane*2;            // this lane's two elements
  float mu0 = muA[i0], mu1 = muA[i0+1];
  float p0 = 1.0f - mu0, p1 = 1.0f - mu1;
  unsigned f0 = (i0==0) || (bmask[i0] != 0);
  unsigned f1 = (bmask[i0+1] != 0);
  // lane aggregate (left-to-right)
  float    sp_ = f1 ? p1 : p0*p1;
  unsigned sf_ = f0|f1;
  // inclusive segmented scan across 64 lane-aggregates
  #pragma unroll
  for (int off=1; off<64; off<<=1){
    float    op = __shfl_up(sp_, off);
    unsigned of = __shfl_up(sf_, off);
    if (lane >= off && !sf_){ sp_ = op*sp_; sf_ = of; }
  }
  if (lane==63){ aggP[wid]=sp_; aggF[wid]=sf_; }
  __syncthreads();
  // wave 0 scans the 16 wave aggregates
  if (wid==0 && lane<16){
    float ap = aggP[lane]; unsigned af = aggF[lane];
    #pragma unroll
    for (int off=1; off<16; off<<=1){
      float    op = __shfl_up(ap, off);
      unsigned of = __shfl_up(af, off);
      if (lane >= off && !af){ ap = op*ap; af = of; }
    }
    wprP[lane]=ap; wprF[lane]=af;
  }
  __syncthreads();
  // full exclusive prefix for this lane's first element
  float    wpP = (wid==0)? 1.0f : wprP[wid-1];
  unsigned wpF = (wid==0)? 0u   : wprF[wid-1];
  float    lpP = __shfl_up(sp_, 1);
  unsigned lpF = __shfl_up(sf_, 1);
  float exP; 
  if (lane==0){ exP = wpP; }
  else        { exP = lpF ? lpP : wpP*lpP; }
  // element inclusives
  float i0P = f0 ? p0 : exP*p0;
  float i1P = f1 ? p1 : i0P*p1;
  float prev0 = (i0==0)? -1.0f : (1.0f - exP);
  float prev1 = 1.0f - i0P;
  float rf0 = 1.0f - i0P, rf1 = 1.0f - i1P;
  // outputs
  out[i0]   = rf0;  out[i0+1]   = rf1;
  out[TSEQ+i0] = mu0; out[TSEQ+i0+1] = mu1;
  out[2*TSEQ+i0] = phiA[i0]; out[2*TSEQ+i0+1] = phiA[i0+1];
  float old0 = prevg[i0], old1 = prevg[i0+1];
  prevg[i0] = prev0; prevg[i0+1] = prev1;
  if (fabsf(prev0 - old0) > 1e-3f){ int pos = atomicAdd(&cnt,1); dlist[pos] = i0; }
  if (fabsf(prev1 - old1) > 1e-3f){ int pos = atomicAdd(&cnt,1); dlist[pos] = i0+1; }
  __syncthreads();
  if (tid==0) *dcnt = cnt;
}

extern "C" void kernel_launch(void* const* d_in, const int* in_sizes, int n_in,
                              void* d_out, int out_size, void* d_ws, size_t ws_size,
                              hipStream_t stream) {
  const float* mol       = (const float*)d_in[0];
  const float* ratios    = (const float*)d_in[1];
  const float* desc      = (const float*)d_in[2];
  const float* svvec     = (const float*)d_in[3];
  const unsigned char* bmask = (const unsigned char*)d_in[4];
  const float* sp_proj_w = (const float*)d_in[5];
  const float* sp_proj_b = (const float*)d_in[6];
  const float* sp_fc1_w  = (const float*)d_in[7];
  const float* sp_fc1_b  = (const float*)d_in[8];
  const float* sp_fc2_w  = (const float*)d_in[9];
  const float* sp_fc2_b  = (const float*)d_in[10];
  const float* sp_ln_g   = (const float*)d_in[11];
  const float* sp_ln_b   = (const float*)d_in[12];
  const float* desc_w    = (const float*)d_in[13];
  const float* desc_b    = (const float*)d_in[14];
  const float* bh_proj_w = (const float*)d_in[15];
  const float* bh_proj_b = (const float*)d_in[16];
  const float* bh_fc1_w  = (const float*)d_in[17];
  const float* bh_fc1_b  = (const float*)d_in[18];
  const float* bh_fc2_w  = (const float*)d_in[19];
  const float* bh_fc2_b  = (const float*)d_in[20];
  const float* bh_ln_g   = (const float*)d_in[21];
  const float* bh_ln_b   = (const float*)d_in[22];
  const float* mu_w      = (const float*)d_in[23];
  const float* mu_b      = (const float*)d_in[24];
  const float* phi_w     = (const float*)d_in[25];
  const float* phi_b     = (const float*)d_in[26];
  float* out = (float*)d_out;

  char* p = (char*)d_ws;
  auto alloc = [&](size_t bytes)->char*{ char* r = p; p += (bytes + 255) & ~(size_t)255; return r; };
  const size_t MM = (size_t)MDIM*MDIM;
  __bf16* Xb   = (__bf16*)alloc((size_t)TSEQ*XLDB*2);    // bf16 [sp|demb]
  __bf16* Zb   = (__bf16*)alloc((size_t)TSEQ*MDIM*2);    // head bf16 z
  float*  Y    = (float*)alloc((size_t)TSEQ*MDIM*4);     // fp32 pre-LN
  float*  ZP   = (float*)alloc((size_t)TSEQ*MDIM*4);     // persistent head pre-activation
  __bf16* Hb16 = (__bf16*)alloc((size_t)TSEQ*MDIM*2);
  __bf16* WALL = (__bf16*)alloc(12*MM*2);                // W1T|W2T|U1T|U2T (3 blocks each)
  __bf16* WpT  = (__bf16*)alloc((size_t)MDIM*XLDB*2);    // [1024][1088]
  float*  PART = (float*)alloc((size_t)16*NRED*4);
  float*  P    = (float*)alloc((size_t)NSOL*MDIM*4);
  float*  mp   = (float*)alloc(MDIM*4);
  float*  prevg= (float*)alloc(TSEQ*4);
  float*  muA  = (float*)alloc(TSEQ*4);
  float*  phiA = (float*)alloc(TSEQ*4);
  int*    dlist= (int*)alloc(TSEQ*4);
  int*    dcnt = (int*)alloc(256);
  __bf16* W1T = WALL, *W2T = WALL + 3*MM, *U1T = WALL + 6*MM, *U2T = WALL + 9*MM;

  k_cvtT13<<<dim3(32,34,13),256,0,stream>>>(sp_fc1_w, sp_fc2_w, bh_fc1_w, bh_fc2_w,
      bh_proj_w + MM, WALL, WpT);
  k_pm<<<dim3(4,6,16),256,0,stream>>>(svvec, sp_proj_w, mol, bh_proj_w, PART);
  k_red<<<dim3(NRED/256),256,0,stream>>>(PART, bh_proj_b, P, mp, prevg, dlist, dcnt);
  k_sp0d<<<dim3(5,TSEQ),256,0,stream>>>(ratios, P, sp_proj_b, desc, desc_w, desc_b, Xb);

  const float* wlast = bh_proj_w + (size_t)2112*MDIM;
  // sp residual chain (bf16 MFMA GEMMs, BK=128)
  for (int i=0;i<NBLK;i++){
    k_mfma_gemm<128,true,false,false,true,false><<<dim3(16,16),512,0,stream>>>(
        Xb, XLDB, MDIM, W1T + i*MM, sp_fc1_b + i*MDIM, nullptr, 0,
        nullptr, 0, Hb16, MDIM, nullptr, nullptr, nullptr);
    k_mfma_gemm<128,false,true,true,false,false><<<dim3(16,16),512,0,stream>>>(
        Hb16, MDIM, MDIM, W2T + i*MM, sp_fc2_b + i*MDIM, Xb, XLDB,
        Y, MDIM, nullptr, 0, nullptr, nullptr, nullptr);
    k_ln<false><<<dim3(TSEQ),256,0,stream>>>(Y, MDIM, Xb, XLDB,
        sp_ln_g + i*MDIM, sp_ln_b + i*MDIM,
        nullptr, nullptr, nullptr, nullptr, nullptr, nullptr);
  }
  // z_pre GEMM (K=1088, BK=64) with fused z0 epilogue: ZP + speculative gelu -> Zb
  k_mfma_gemm<64,false,false,true,false,true><<<dim3(16,16),512,0,stream>>>(
      Xb, XLDB, XLDB, WpT, mp, nullptr, 0, ZP, MDIM, nullptr, 0,
      wlast, prevg, Zb);

  // ---- iteration 1: batched head with speculative prev ----
  for (int i=0;i<NBLK;i++){
    k_mfma_gemm<128,true,false,false,true,false><<<dim3(16,16),512,0,stream>>>(
        Zb, MDIM, MDIM, U1T + i*MM, bh_fc1_b + i*MDIM, nullptr, 0,
        nullptr, 0, Hb16, MDIM, nullptr, nullptr, nullptr);
    k_mfma_gemm<128,false,true,true,false,false><<<dim3(16,16),512,0,stream>>>(
        Hb16, MDIM, MDIM, U2T + i*MM, bh_fc2_b + i*MDIM, Zb, MDIM,
        Y, MDIM, nullptr, 0, nullptr, nullptr, nullptr);
    if (i < NBLK-1)
      k_ln<false><<<dim3(TSEQ),256,0,stream>>>(Y, MDIM, Zb, MDIM,
          bh_ln_g + i*MDIM, bh_ln_b + i*MDIM,
          nullptr, nullptr, nullptr, nullptr, nullptr, nullptr);
    else
      k_ln<true><<<dim3(TSEQ),256,0,stream>>>(Y, MDIM, Zb, MDIM,
          bh_ln_g + i*MDIM, bh_ln_b + i*MDIM,
          mu_w, mu_b, phi_w, phi_b, muA, phiA);
  }
  k_scan<<<dim3(1),1024,0,stream>>>(muA, phiA, bmask, prevg, dlist, dcnt, out);

  // ---- refinement: one staged dirty-row pass + final scan ----
  for (int it=1; it<KITER; it++){
    k_fc1z_dirty<<<dim3(16,RST),64,0,stream>>>(ZP, wlast, prevg,
        U1T, bh_fc1_b, dlist, dcnt, Zb, Hb16);
    k_fc2_dirty<<<dim3(16,RST),64,0,stream>>>(
        Hb16, U2T, bh_fc2_b, Zb, dlist, dcnt, Y);
    for (int i=1;i<NBLK;i++){
      k_lnfc1_dirty<<<dim3(16,RST),64,0,stream>>>(Y,
          bh_ln_g + (i-1)*MDIM, bh_ln_b + (i-1)*MDIM,
          U1T + i*MM, bh_fc1_b + i*MDIM, dlist, dcnt, Zb, Hb16);
      k_fc2_dirty<<<dim3(16,RST),64,0,stream>>>(
          Hb16, U2T + i*MM, bh_fc2_b + i*MDIM, Zb, dlist, dcnt, Y);
    }
    k_lnmp_dirty<<<dim3(RST),64,0,stream>>>(Y,
        bh_ln_g + (NBLK-1)*MDIM, bh_ln_b + (NBLK-1)*MDIM,
        dlist, dcnt, mu_w, mu_b, phi_w, phi_b, muA, phiA);
    k_scan<<<dim3(1),1024,0,stream>>>(muA, phiA, bmask, prevg, dlist, dcnt, out);
  }
  (void)in_sizes; (void)n_in; (void)out_size; (void)ws_size;
}